// Round 18
// baseline (653.895 us; speedup 1.0000x reference)
//
#include <hip/hip_runtime.h>
#include <math.h>

// LegacyVMambaBlock R18: conv_scan MLP (memory-level parallelism) bump —
// conv loop unroll 2 (18 outstanding loads/wave vs 9), store loop fully
// unrolled, plain __launch_bounds__(512) (128-VGPR cap, R8-proven) so the
// unrolled body (~100 live) doesn't spill. Everything else = R17.

typedef __attribute__((ext_vector_type(8))) short bf16x8;
typedef __attribute__((ext_vector_type(4))) float f32x4;

#define T_TOKENS 65536
#define DMODEL 384
#define DINNER 768
#define DHIDDEN 1536

__device__ __forceinline__ float bf2f(unsigned short u) {
  unsigned int x = ((unsigned int)u) << 16;
  return __builtin_bit_cast(float, x);
}
__device__ __forceinline__ unsigned short f2bf(float f) {
  unsigned int x = __builtin_bit_cast(unsigned int, f);
  x += 0x7fffu + ((x >> 16) & 1u);
  return (unsigned short)(x >> 16);
}
__device__ __forceinline__ void unpack2(unsigned int u, float& lo, float& hi) {
  lo = __builtin_bit_cast(float, u << 16);
  hi = __builtin_bit_cast(float, u & 0xffff0000u);
}
__device__ __forceinline__ unsigned int pack2(float lo, float hi) {
  return (unsigned int)f2bf(lo) | ((unsigned int)f2bf(hi) << 16);
}
// truncating pack (3 ops): <=1 ULP bf16 noise, conv_scan-internal only
__device__ __forceinline__ unsigned int pack2t(float lo, float hi) {
  return (__builtin_bit_cast(unsigned int, lo) >> 16) |
         (__builtin_bit_cast(unsigned int, hi) & 0xffff0000u);
}

__device__ __forceinline__ void gload16(const void* g, void* l) {
  __builtin_amdgcn_global_load_lds(
      (const __attribute__((address_space(1))) void*)g,
      (__attribute__((address_space(3))) void*)l, 16, 0, 0);
}

// ---------- weight prep helper ----------
__device__ __forceinline__ void wprep_tile(const float* __restrict__ in,
                                           unsigned short* __restrict__ out,
                                           int K, int N, int k0, int n0,
                                           int tid, float t[32][33]) {
  const int a = tid & 31, b8 = tid >> 5;
#pragma unroll
  for (int i = 0; i < 4; i++)
    t[b8 + 8 * i][a] = in[(size_t)(k0 + b8 + 8 * i) * N + n0 + a];
  __syncthreads();
#pragma unroll
  for (int i = 0; i < 4; i++)
    out[(size_t)(n0 + b8 + 8 * i) * K + k0 + a] = f2bf(t[a][b8 + 8 * i]);
}

// ---------- fused LN over f32 [T,384] -> bf16 + w_in prep (merged) ----------
__global__ __launch_bounds__(256) void ln1_wprep_kernel(
    const float* __restrict__ in, const float* __restrict__ g,
    const float* __restrict__ b, unsigned short* __restrict__ out,
    const float* __restrict__ win, unsigned short* __restrict__ wTin) {
  __shared__ float t[32][33];
  if (blockIdx.x >= 16384) {
    const int id = blockIdx.x - 16384;  // 288 tiles: 12 x 24
    wprep_tile(win, wTin, DMODEL, DINNER, (id % 12) * 32, (id / 12) * 32,
               threadIdx.x, t);
    return;
  }
  const int tok = blockIdx.x * 4 + (threadIdx.x >> 6);
  const int lane = threadIdx.x & 63;
  const float2* row = (const float2*)(in + (size_t)tok * 384);
  float2 v[3];
  float s = 0.f, ss = 0.f;
#pragma unroll
  for (int k = 0; k < 3; k++) {
    v[k] = row[lane + 64 * k];
    s += v[k].x + v[k].y;
    ss += v[k].x * v[k].x + v[k].y * v[k].y;
  }
#pragma unroll
  for (int off = 32; off > 0; off >>= 1) {
    s += __shfl_xor(s, off);
    ss += __shfl_xor(ss, off);
  }
  const float m = s * (1.0f / 384.0f);
  const float r = rsqrtf(ss * (1.0f / 384.0f) - m * m + 1e-5f);
  unsigned int* op = (unsigned int*)(out + (size_t)tok * 384);
#pragma unroll
  for (int k = 0; k < 3; k++) {
    const int c = lane + 64 * k;
    const float2 gg = ((const float2*)g)[c];
    const float2 bb = ((const float2*)b)[c];
    op[c] = pack2((v[k].x - m) * r * gg.x + bb.x, (v[k].y - m) * r * gg.y + bb.y);
  }
}

// ---------- plain fused LN over f32 [T,384] -> bf16 (LN2) ----------
__global__ __launch_bounds__(256) void ln_fused_f32_384(
    const float* __restrict__ in, const float* __restrict__ g,
    const float* __restrict__ b, unsigned short* __restrict__ out) {
  const int tok = blockIdx.x * 4 + (threadIdx.x >> 6);
  const int lane = threadIdx.x & 63;
  const float2* row = (const float2*)(in + (size_t)tok * 384);
  float2 v[3];
  float s = 0.f, ss = 0.f;
#pragma unroll
  for (int k = 0; k < 3; k++) {
    v[k] = row[lane + 64 * k];
    s += v[k].x + v[k].y;
    ss += v[k].x * v[k].x + v[k].y * v[k].y;
  }
#pragma unroll
  for (int off = 32; off > 0; off >>= 1) {
    s += __shfl_xor(s, off);
    ss += __shfl_xor(ss, off);
  }
  const float m = s * (1.0f / 384.0f);
  const float r = rsqrtf(ss * (1.0f / 384.0f) - m * m + 1e-5f);
  unsigned int* op = (unsigned int*)(out + (size_t)tok * 384);
#pragma unroll
  for (int k = 0; k < 3; k++) {
    const int c = lane + 64 * k;
    const float2 gg = ((const float2*)g)[c];
    const float2 bb = ((const float2*)b)[c];
    op[c] = pack2((v[k].x - m) * r * gg.x + bb.x, (v[k].y - m) * r * gg.y + bb.y);
  }
}

// ---------- LN over bundle8 bf16 [cell192][b][pos][4ch] -> token-major ------
__global__ __launch_bounds__(256) void ln_bundle_768(
    const uint2* __restrict__ mixed, const float* __restrict__ g,
    const float* __restrict__ b, uint2* __restrict__ out) {
  const int tid = threadIdx.x;
  const int tk = tid >> 2, j = tid & 3;
  const int token = blockIdx.x * 64 + tk;
  const int bb_ = token >> 12, posb = token & 4095;
  const size_t slab = (size_t)bb_ * 4096 + posb;
  float s = 0.f, ss = 0.f;
#pragma unroll 1
  for (int cg = j; cg < 192; cg += 4) {
    const uint2 v = mixed[((size_t)cg * 16) * 4096 + slab];
    float e0, e1, e2, e3;
    unpack2(v.x, e0, e1);
    unpack2(v.y, e2, e3);
    s += (e0 + e1) + (e2 + e3);
    ss += e0 * e0 + e1 * e1 + e2 * e2 + e3 * e3;
  }
  s += __shfl_xor(s, 1); ss += __shfl_xor(ss, 1);
  s += __shfl_xor(s, 2); ss += __shfl_xor(ss, 2);
  const float m = s * (1.0f / 768.0f);
  const float r = rsqrtf(ss * (1.0f / 768.0f) - m * m + 1e-5f);
  const size_t tokbase = (size_t)token * 192;
#pragma unroll 1
  for (int cg = j; cg < 192; cg += 4) {
    const uint2 v = mixed[((size_t)cg * 16) * 4096 + slab];
    const float4 gg = ((const float4*)g)[cg];
    const float4 bb4 = ((const float4*)b)[cg];
    float e0, e1, e2, e3;
    unpack2(v.x, e0, e1);
    unpack2(v.y, e2, e3);
    uint2 o;
    o.x = pack2((e0 - m) * r * gg.x + bb4.x, (e1 - m) * r * gg.y + bb4.y);
    o.y = pack2((e2 - m) * r * gg.z + bb4.z, (e3 - m) * r * gg.w + bb4.w);
    out[tokbase + cg] = o;
  }
}

// merged prep of w_out^T, w1^T, w2^T (one launch; runs after ln_bundle)
__global__ __launch_bounds__(256) void wprep3_kernel(
    const float* __restrict__ wout, unsigned short* __restrict__ wToutp,
    const float* __restrict__ w1, unsigned short* __restrict__ wT1p,
    const float* __restrict__ w2, unsigned short* __restrict__ wT2p) {
  __shared__ float t[32][33];
  int id = blockIdx.x;
  if (id < 288) {  // w_out: K=768, N=384
    wprep_tile(wout, wToutp, 768, 384, (id / 12) * 32, (id % 12) * 32,
               threadIdx.x, t);
  } else if (id < 864) {  // w1: K=384, N=1536
    id -= 288;
    wprep_tile(w1, wT1p, 384, 1536, (id / 48) * 32, (id % 48) * 32,
               threadIdx.x, t);
  } else {  // w2: K=1536, N=384
    id -= 864;
    wprep_tile(w2, wT2p, 1536, 384, (id / 12) * 32, (id % 12) * 32,
               threadIdx.x, t);
  }
}

// ---------- GEMM BK=32 2-phase dbuf, 4 blocks/CU (proven R14) ----------
template <int EPI>
__global__ __launch_bounds__(256, 4) void gemm_bt_kernel(
    const unsigned short* __restrict__ A, int lda,
    const unsigned short* __restrict__ Bt, int ldb, int KT,
    const float* __restrict__ bias, const float* __restrict__ res,
    void* __restrict__ C, int ldc, int nby) {
  __shared__ unsigned short smem[16640];  // 33.28KB
  char* const smc = (char*)smem;

  const int tid = threadIdx.x;
  const int w = tid >> 6, lane = tid & 63;
  const int cpx = gridDim.x >> 3;
  const int g = blockIdx.x;
  const int sw = (g & 7) * cpx + (g >> 3);
  const int bx = sw / nby, by = sw - bx * nby;
  const int tok0 = bx << 7, n0 = by << 7;

  const int wm = w >> 1, wn = w & 1;
  const int lrow = lane & 15, kgrp = lane >> 4;

  const int lr4 = lane >> 2;
  const int r0 = (w * 2 + 0) * 16 + lr4;
  const int r1 = (w * 2 + 1) * 16 + lr4;
  const int c0 = ((lane & 3) ^ ((r0 >> 1) & 3)) << 3;
  const int c1 = ((lane & 3) ^ ((r1 >> 1) & 3)) << 3;
  const unsigned short* A0 = A + (size_t)(tok0 + r0) * lda + c0;
  const unsigned short* A1p = A + (size_t)(tok0 + r1) * lda + c1;
  const unsigned short* B0 = Bt + (size_t)(n0 + r0) * ldb + c0;
  const unsigned short* B1 = Bt + (size_t)(n0 + r1) * ldb + c1;
  const int d0 = (w * 2 + 0) * 1024;
  const int d1 = (w * 2 + 1) * 1024;

  f32x4 acc[4][4];
#pragma unroll
  for (int i = 0; i < 4; i++)
#pragma unroll
    for (int j = 0; j < 4; j++) {
      f32x4 z = {0.f, 0.f, 0.f, 0.f};
      acc[i][j] = z;
    }

  const int nt = KT >> 5;
  gload16(A0, smc + d0);
  gload16(A1p, smc + d1);
  gload16(B0, smc + 16384 + d0);
  gload16(B1, smc + 16384 + d1);
  __syncthreads();

  int buf = 0;
  for (int t = 0; t < nt; t++) {
    if (t + 1 < nt) {
      const int kt = (t + 1) << 5;
      const int bo = (buf ^ 1) * 8192;
      gload16(A0 + kt, smc + bo + d0);
      gload16(A1p + kt, smc + bo + d1);
      gload16(B0 + kt, smc + 16384 + bo + d0);
      gload16(B1 + kt, smc + 16384 + bo + d1);
    }
    const int bo = buf * 8192;
    bf16x8 af[4], bf_[4];
#pragma unroll
    for (int f = 0; f < 4; f++) {
      const int ra = wm * 64 + f * 16 + lrow;
      const int rb = wn * 64 + f * 16 + lrow;
      af[f] = *(const bf16x8*)(smc + bo + ra * 64 +
                               ((kgrp ^ ((ra >> 1) & 3)) << 4));
      bf_[f] = *(const bf16x8*)(smc + 16384 + bo + rb * 64 +
                                ((kgrp ^ ((rb >> 1) & 3)) << 4));
    }
#pragma unroll
    for (int mf = 0; mf < 4; mf++)
#pragma unroll
      for (int nf = 0; nf < 4; nf++)
        acc[mf][nf] = __builtin_amdgcn_mfma_f32_16x16x32_bf16(
            af[mf], bf_[nf], acc[mf][nf], 0, 0, 0);
    __syncthreads();
    buf ^= 1;
  }

  if constexpr (EPI == 3) {
#pragma unroll
    for (int mf = 0; mf < 4; mf++)
#pragma unroll
      for (int nf = 0; nf < 4; nf++) {
        const int cl = wn * 64 + nf * 16 + lrow;
        const float bv = bias[n0 + cl];
#pragma unroll
        for (int r = 0; r < 4; r++) {
          const int tl = wm * 64 + mf * 16 + kgrp * 4 + r;
          smem[(cl >> 2) * 520 + tl * 4 + (cl & 3)] =
              f2bf(acc[mf][nf][r] + bv);
        }
      }
    __syncthreads();
    const int bb_ = tok0 >> 12, pos0 = tok0 & 4095, cg0 = n0 >> 2;
    uint2* Cb = (uint2*)C;
#pragma unroll
    for (int e = 0; e < 16; e++) {
      const int lin = e * 256 + tid;
      const int cgl = lin >> 7, pp = lin & 127;
      const uint2 v = *(const uint2*)&smem[cgl * 520 + pp * 4];
      Cb[((size_t)(cg0 + cgl) * 16 + bb_) * 4096 + pos0 + pp] = v;
    }
  } else {
#pragma unroll
    for (int mf = 0; mf < 4; mf++) {
#pragma unroll
      for (int nf = 0; nf < 4; nf++) {
        const int gcol = n0 + wn * 64 + nf * 16 + lrow;
        const float bv = bias ? bias[gcol] : 0.0f;
#pragma unroll
        for (int r = 0; r < 4; r++) {
          const int grow = tok0 + wm * 64 + mf * 16 + kgrp * 4 + r;
          float v = acc[mf][nf][r] + bv;
          const size_t idx = (size_t)grow * ldc + gcol;
          if constexpr (EPI == 1) {
            ((float*)C)[idx] = v + res[idx];
          } else {
            const float z = 1.5957691216057308f * (v + 0.044715f * v * v * v);
            const float gl = v / (1.0f + __expf(-z));
            ((unsigned short*)C)[idx] = f2bf(gl);
          }
        }
      }
    }
  }
}

// ---------- segmented bidirectional EMA, float results ----------
__device__ __forceinline__ void ema_seg_f(const unsigned int vals[16],
                                          const int seg, float rl[16],
                                          float rh[16]) {
  const float A16 = 2.8211099e-4f;   // 0.6^16
  const float A32 = 7.9586611e-8f;   // 0.6^32
  float a, bv, t;
  float za = 0.f, zb = 0.f;
#pragma unroll
  for (int j = 0; j < 16; j++) {
    unpack2(vals[j], a, bv);
    za = 0.6f * za + 0.4f * a;
    zb = 0.6f * zb + 0.4f * bv;
  }
  t = __shfl_up(za, 1); if (seg >= 1) za += A16 * t;
  t = __shfl_up(zb, 1); if (seg >= 1) zb += A16 * t;
  t = __shfl_up(za, 2); if (seg >= 2) za += A32 * t;
  t = __shfl_up(zb, 2); if (seg >= 2) zb += A32 * t;
  float yfa = __shfl_up(za, 1), yfb = __shfl_up(zb, 1);
  if (seg == 0) { yfa = 0.f; yfb = 0.f; }
  float ua = 0.f, ub = 0.f;
#pragma unroll
  for (int j = 15; j >= 0; j--) {
    unpack2(vals[j], a, bv);
    ua = 0.6f * ua + 0.4f * a;
    ub = 0.6f * ub + 0.4f * bv;
  }
  t = __shfl_down(ua, 1); if (seg <= 2) ua += A16 * t;
  t = __shfl_down(ub, 1); if (seg <= 2) ub += A16 * t;
  t = __shfl_down(ua, 2); if (seg <= 1) ua += A32 * t;
  t = __shfl_down(ub, 2); if (seg <= 1) ub += A32 * t;
  float zba = __shfl_down(ua, 1), zbb = __shfl_down(ub, 1);
  if (seg == 3) { zba = 0.f; zbb = 0.f; }
  float fa = yfa, fb = yfb;
#pragma unroll
  for (int j = 0; j < 16; j++) {
    unpack2(vals[j], a, bv);
    fa = 0.6f * fa + 0.4f * a;
    fb = 0.6f * fb + 0.4f * bv;
    rl[j] = fa;
    rh[j] = fb;
  }
  float ga = zba, gb = zbb;
#pragma unroll
  for (int j = 15; j >= 0; j--) {
    unpack2(vals[j], a, bv);
    ga = 0.6f * ga + 0.4f * a;
    gb = 0.6f * gb + 0.4f * bv;
    rl[j] = 0.25f * (rl[j] + ga);
    rh[j] = 0.25f * (rh[j] + gb);
  }
}

// ---------- fused dwconv3x3 + 4 EMA scans on bundle8 layout ----------
// 512 threads, plain bounds (128-VGPR cap). Conv loop unroll 2 for 2x
// memory-level parallelism in the latency-bound phase.
__global__ __launch_bounds__(512) void conv_scan_kernel(
    const uint2* __restrict__ p, const float* __restrict__ kconv,
    uint2* __restrict__ mixed) {
  __shared__ unsigned int loc[2][64][65];  // 33.28 KB
  __shared__ float klds[36];
  const int tid = threadIdx.x;
  const int c = blockIdx.x;   // cell 0..191
  const int b = blockIdx.y;   // 0..15
  const uint2* pb = p + ((size_t)c * 16 + b) * 4096;

  if (tid < 36) klds[tid] = kconv[(tid >> 2) * DINNER + c * 4 + (tid & 3)];
  __syncthreads();

#pragma unroll 2
  for (int i = 0; i < 8; i++) {
    const int pos = tid + 512 * i;
    const int h = pos >> 6, w = pos & 63;
    float a0 = 0.f, a1 = 0.f, a2 = 0.f, a3 = 0.f;
#pragma unroll
    for (int dh = 0; dh < 3; dh++) {
      const int hh = h + dh - 1;
      const bool vh = (unsigned)hh < 64u;
      const int hcl = min(max(hh, 0), 63);
#pragma unroll
      for (int dw = 0; dw < 3; dw++) {
        const int ww = w + dw - 1;
        const bool vv = vh && ((unsigned)ww < 64u);
        const int wcl = min(max(ww, 0), 63);
        uint2 pv = pb[hcl * 64 + wcl];
        if (!vv) { pv.x = 0; pv.y = 0; }
        const int t = dh * 3 + dw;
        float lo, hi;
        unpack2(pv.x, lo, hi);
        a0 += lo * klds[t * 4 + 0];
        a1 += hi * klds[t * 4 + 1];
        unpack2(pv.y, lo, hi);
        a2 += lo * klds[t * 4 + 2];
        a3 += hi * klds[t * 4 + 3];
      }
    }
    loc[0][h][w] = pack2t(a0, a1);
    loc[1][h][w] = pack2t(a2, a3);
  }
  __syncthreads();

  const int seg = tid & 3;
  const int ax = (tid >> 2) & 63;
  const int cp = tid >> 8;
  const int j0 = seg * 16;

  float hcl_[16], hch_[16];
  {
    unsigned int vals[16];
#pragma unroll
    for (int j = 0; j < 16; j++) vals[j] = loc[cp][j0 + j][ax];
    ema_seg_f(vals, seg, hcl_, hch_);
  }
  __syncthreads();

  {
    unsigned int vals[16];
    float wl[16], wh[16];
#pragma unroll
    for (int j = 0; j < 16; j++) vals[j] = loc[cp][ax][j0 + j];
    ema_seg_f(vals, seg, wl, wh);
#pragma unroll
    for (int j = 0; j < 16; j++) {
      float a, bv;
      unpack2(vals[j], a, bv);
      loc[cp][ax][j0 + j] = pack2t(a + wl[j], bv + wh[j]);
    }
  }
  __syncthreads();

#pragma unroll
  for (int j = 0; j < 16; j++) {
    float a, bv;
    unpack2(loc[cp][j0 + j][ax], a, bv);
    loc[cp][j0 + j][ax] = pack2t(a + hcl_[j], bv + hch_[j]);
  }
  __syncthreads();

  uint2* mb = mixed + ((size_t)c * 16 + b) * 4096;
#pragma unroll
  for (int i = 0; i < 8; i++) {
    const int pos = tid + 512 * i;
    const int h = pos >> 6, w = pos & 63;
    uint2 st;
    st.x = loc[0][h][w];
    st.y = loc[1][h][w];
    mb[pos] = st;
  }
}

extern "C" void kernel_launch(void* const* d_in, const int* in_sizes, int n_in,
                              void* d_out, int out_size, void* d_ws,
                              size_t ws_size, hipStream_t stream) {
  const float* x = (const float*)d_in[0];
  const float* n1_g = (const float*)d_in[1];
  const float* n1_b = (const float*)d_in[2];
  const float* w_in = (const float*)d_in[3];
  const float* b_in = (const float*)d_in[4];
  const float* k_conv = (const float*)d_in[5];
  const float* on_g = (const float*)d_in[6];
  const float* on_b = (const float*)d_in[7];
  const float* w_out = (const float*)d_in[8];
  const float* b_out = (const float*)d_in[9];
  const float* n2_g = (const float*)d_in[10];
  const float* n2_b = (const float*)d_in[11];
  const float* w1 = (const float*)d_in[12];
  const float* b1 = (const float*)d_in[13];
  const float* w2 = (const float*)d_in[14];
  const float* b2 = (const float*)d_in[15];

  const size_t MB = 1024 * 1024;
  char* ws = (char*)d_ws;
  unsigned short* R1 = (unsigned short*)(ws + 3 * MB / 2);
  unsigned short* R2 = (unsigned short*)(ws + 3 * MB / 2 + 96 * MB);

  unsigned short* A1 = R2;                         // 48MB token-major
  unsigned short* wTin = R2 + (48 * MB) / 2;       // [768][384]
  unsigned short* p = R1;                          // 96MB BUNDLE8; in-place
  unsigned short* A2 = R2;                         // 96MB token-major
  unsigned short* wTout = R1;                      // [384][768] (p dead)
  unsigned short* A3 = R1;                         // 48MB
  unsigned short* wT1 = R1 + (48 * MB) / 2;        // [1536][384]
  unsigned short* wT2 = wT1 + (size_t)1536 * 384;  // [384][1536]
  unsigned short* gb = R2;                         // 96MB token-major

  float* out = (float*)d_out;
  dim3 b256(256);

  // LN1(x) -> A1, merged with w_in^T prep (disjoint R2 regions)
  ln1_wprep_kernel<<<16384 + 288, b256, 0, stream>>>(x, n1_g, n1_b, A1, w_in,
                                                     wTin);
  // p(bundle8) = A1 @ w_in + b_in
  gemm_bt_kernel<3><<<3072, b256, 0, stream>>>(A1, DMODEL, wTin, DMODEL, DMODEL,
                                               b_in, nullptr, p, DINNER, 6);
  // mixed(bundle8) = conv+scan(p), in place
  conv_scan_kernel<<<dim3(192, 16), dim3(512), 0, stream>>>(
      (const uint2*)p, k_conv, (uint2*)p);
  // LN(on)(mixed bundle8) -> A2 token-major
  ln_bundle_768<<<1024, b256, 0, stream>>>((const uint2*)p, on_g, on_b,
                                           (uint2*)A2);
  // merged prep: w_out^T, w1^T, w2^T (p dead after ln_bundle)
  wprep3_kernel<<<1440, b256, 0, stream>>>(w_out, wTout, w1, wT1, w2, wT2);
  // out = x + A2 @ w_out + b_out
  gemm_bt_kernel<1><<<1536, b256, 0, stream>>>(A2, DINNER, wTout, DINNER, DINNER,
                                               b_out, x, out, DMODEL, 3);
  // LN2(out) -> A3
  ln_fused_f32_384<<<T_TOKENS / 4, b256, 0, stream>>>(out, n2_g, n2_b, A3);
  // MLP split by tokens
  for (int hh = 0; hh < 2; hh++) {
    const size_t toff = (size_t)hh * 32768;
    gemm_bt_kernel<2><<<3072, b256, 0, stream>>>(
        A3 + toff * DMODEL, DMODEL, wT1, DMODEL, DMODEL, b1, nullptr, gb,
        DHIDDEN, 12);
    gemm_bt_kernel<1><<<768, b256, 0, stream>>>(
        gb, DHIDDEN, wT2, DHIDDEN, DHIDDEN, b2, out + toff * DMODEL,
        out + toff * DMODEL, DMODEL, 3);
  }
}

// Round 19
// 641.302 us; speedup vs baseline: 1.0196x; 1.0196x over previous
//
#include <hip/hip_runtime.h>
#include <math.h>

// LegacyVMambaBlock R19: conv_scan input staged to LDS (inp[2][64][65]) in one
// coalesced pass; the 9-tap conv then reads LDS (~6cyc) instead of L1/L2
// (~200cyc x 72 loads/thread) — attacks the measured latency-bound conv
// phase. LDS 66.6KB still = 2 blocks/CU (VGPR-capped anyway). Everything
// else = R17/R18 proven (bundle8, BK=32 GEMMs, merged preps).

typedef __attribute__((ext_vector_type(8))) short bf16x8;
typedef __attribute__((ext_vector_type(4))) float f32x4;

#define T_TOKENS 65536
#define DMODEL 384
#define DINNER 768
#define DHIDDEN 1536

__device__ __forceinline__ float bf2f(unsigned short u) {
  unsigned int x = ((unsigned int)u) << 16;
  return __builtin_bit_cast(float, x);
}
__device__ __forceinline__ unsigned short f2bf(float f) {
  unsigned int x = __builtin_bit_cast(unsigned int, f);
  x += 0x7fffu + ((x >> 16) & 1u);
  return (unsigned short)(x >> 16);
}
__device__ __forceinline__ void unpack2(unsigned int u, float& lo, float& hi) {
  lo = __builtin_bit_cast(float, u << 16);
  hi = __builtin_bit_cast(float, u & 0xffff0000u);
}
__device__ __forceinline__ unsigned int pack2(float lo, float hi) {
  return (unsigned int)f2bf(lo) | ((unsigned int)f2bf(hi) << 16);
}
// truncating pack (3 ops): <=1 ULP bf16 noise, conv_scan-internal only
__device__ __forceinline__ unsigned int pack2t(float lo, float hi) {
  return (__builtin_bit_cast(unsigned int, lo) >> 16) |
         (__builtin_bit_cast(unsigned int, hi) & 0xffff0000u);
}

__device__ __forceinline__ void gload16(const void* g, void* l) {
  __builtin_amdgcn_global_load_lds(
      (const __attribute__((address_space(1))) void*)g,
      (__attribute__((address_space(3))) void*)l, 16, 0, 0);
}

// ---------- weight prep helper ----------
__device__ __forceinline__ void wprep_tile(const float* __restrict__ in,
                                           unsigned short* __restrict__ out,
                                           int K, int N, int k0, int n0,
                                           int tid, float t[32][33]) {
  const int a = tid & 31, b8 = tid >> 5;
#pragma unroll
  for (int i = 0; i < 4; i++)
    t[b8 + 8 * i][a] = in[(size_t)(k0 + b8 + 8 * i) * N + n0 + a];
  __syncthreads();
#pragma unroll
  for (int i = 0; i < 4; i++)
    out[(size_t)(n0 + b8 + 8 * i) * K + k0 + a] = f2bf(t[a][b8 + 8 * i]);
}

// ---------- fused LN over f32 [T,384] -> bf16 + w_in prep (merged) ----------
__global__ __launch_bounds__(256) void ln1_wprep_kernel(
    const float* __restrict__ in, const float* __restrict__ g,
    const float* __restrict__ b, unsigned short* __restrict__ out,
    const float* __restrict__ win, unsigned short* __restrict__ wTin) {
  __shared__ float t[32][33];
  if (blockIdx.x >= 16384) {
    const int id = blockIdx.x - 16384;  // 288 tiles: 12 x 24
    wprep_tile(win, wTin, DMODEL, DINNER, (id % 12) * 32, (id / 12) * 32,
               threadIdx.x, t);
    return;
  }
  const int tok = blockIdx.x * 4 + (threadIdx.x >> 6);
  const int lane = threadIdx.x & 63;
  const float2* row = (const float2*)(in + (size_t)tok * 384);
  float2 v[3];
  float s = 0.f, ss = 0.f;
#pragma unroll
  for (int k = 0; k < 3; k++) {
    v[k] = row[lane + 64 * k];
    s += v[k].x + v[k].y;
    ss += v[k].x * v[k].x + v[k].y * v[k].y;
  }
#pragma unroll
  for (int off = 32; off > 0; off >>= 1) {
    s += __shfl_xor(s, off);
    ss += __shfl_xor(ss, off);
  }
  const float m = s * (1.0f / 384.0f);
  const float r = rsqrtf(ss * (1.0f / 384.0f) - m * m + 1e-5f);
  unsigned int* op = (unsigned int*)(out + (size_t)tok * 384);
#pragma unroll
  for (int k = 0; k < 3; k++) {
    const int c = lane + 64 * k;
    const float2 gg = ((const float2*)g)[c];
    const float2 bb = ((const float2*)b)[c];
    op[c] = pack2((v[k].x - m) * r * gg.x + bb.x, (v[k].y - m) * r * gg.y + bb.y);
  }
}

// ---------- plain fused LN over f32 [T,384] -> bf16 (LN2) ----------
__global__ __launch_bounds__(256) void ln_fused_f32_384(
    const float* __restrict__ in, const float* __restrict__ g,
    const float* __restrict__ b, unsigned short* __restrict__ out) {
  const int tok = blockIdx.x * 4 + (threadIdx.x >> 6);
  const int lane = threadIdx.x & 63;
  const float2* row = (const float2*)(in + (size_t)tok * 384);
  float2 v[3];
  float s = 0.f, ss = 0.f;
#pragma unroll
  for (int k = 0; k < 3; k++) {
    v[k] = row[lane + 64 * k];
    s += v[k].x + v[k].y;
    ss += v[k].x * v[k].x + v[k].y * v[k].y;
  }
#pragma unroll
  for (int off = 32; off > 0; off >>= 1) {
    s += __shfl_xor(s, off);
    ss += __shfl_xor(ss, off);
  }
  const float m = s * (1.0f / 384.0f);
  const float r = rsqrtf(ss * (1.0f / 384.0f) - m * m + 1e-5f);
  unsigned int* op = (unsigned int*)(out + (size_t)tok * 384);
#pragma unroll
  for (int k = 0; k < 3; k++) {
    const int c = lane + 64 * k;
    const float2 gg = ((const float2*)g)[c];
    const float2 bb = ((const float2*)b)[c];
    op[c] = pack2((v[k].x - m) * r * gg.x + bb.x, (v[k].y - m) * r * gg.y + bb.y);
  }
}

// ---------- LN over bundle8 bf16 [cell192][b][pos][4ch] -> token-major ------
__global__ __launch_bounds__(256) void ln_bundle_768(
    const uint2* __restrict__ mixed, const float* __restrict__ g,
    const float* __restrict__ b, uint2* __restrict__ out) {
  const int tid = threadIdx.x;
  const int tk = tid >> 2, j = tid & 3;
  const int token = blockIdx.x * 64 + tk;
  const int bb_ = token >> 12, posb = token & 4095;
  const size_t slab = (size_t)bb_ * 4096 + posb;
  float s = 0.f, ss = 0.f;
#pragma unroll 1
  for (int cg = j; cg < 192; cg += 4) {
    const uint2 v = mixed[((size_t)cg * 16) * 4096 + slab];
    float e0, e1, e2, e3;
    unpack2(v.x, e0, e1);
    unpack2(v.y, e2, e3);
    s += (e0 + e1) + (e2 + e3);
    ss += e0 * e0 + e1 * e1 + e2 * e2 + e3 * e3;
  }
  s += __shfl_xor(s, 1); ss += __shfl_xor(ss, 1);
  s += __shfl_xor(s, 2); ss += __shfl_xor(ss, 2);
  const float m = s * (1.0f / 768.0f);
  const float r = rsqrtf(ss * (1.0f / 768.0f) - m * m + 1e-5f);
  const size_t tokbase = (size_t)token * 192;
#pragma unroll 1
  for (int cg = j; cg < 192; cg += 4) {
    const uint2 v = mixed[((size_t)cg * 16) * 4096 + slab];
    const float4 gg = ((const float4*)g)[cg];
    const float4 bb4 = ((const float4*)b)[cg];
    float e0, e1, e2, e3;
    unpack2(v.x, e0, e1);
    unpack2(v.y, e2, e3);
    uint2 o;
    o.x = pack2((e0 - m) * r * gg.x + bb4.x, (e1 - m) * r * gg.y + bb4.y);
    o.y = pack2((e2 - m) * r * gg.z + bb4.z, (e3 - m) * r * gg.w + bb4.w);
    out[tokbase + cg] = o;
  }
}

// merged prep of w_out^T, w1^T, w2^T (one launch; runs after ln_bundle)
__global__ __launch_bounds__(256) void wprep3_kernel(
    const float* __restrict__ wout, unsigned short* __restrict__ wToutp,
    const float* __restrict__ w1, unsigned short* __restrict__ wT1p,
    const float* __restrict__ w2, unsigned short* __restrict__ wT2p) {
  __shared__ float t[32][33];
  int id = blockIdx.x;
  if (id < 288) {  // w_out: K=768, N=384
    wprep_tile(wout, wToutp, 768, 384, (id / 12) * 32, (id % 12) * 32,
               threadIdx.x, t);
  } else if (id < 864) {  // w1: K=384, N=1536
    id -= 288;
    wprep_tile(w1, wT1p, 384, 1536, (id / 48) * 32, (id % 48) * 32,
               threadIdx.x, t);
  } else {  // w2: K=1536, N=384
    id -= 864;
    wprep_tile(w2, wT2p, 1536, 384, (id / 12) * 32, (id % 12) * 32,
               threadIdx.x, t);
  }
}

// ---------- GEMM BK=32 2-phase dbuf, 4 blocks/CU (proven R14) ----------
template <int EPI>
__global__ __launch_bounds__(256, 4) void gemm_bt_kernel(
    const unsigned short* __restrict__ A, int lda,
    const unsigned short* __restrict__ Bt, int ldb, int KT,
    const float* __restrict__ bias, const float* __restrict__ res,
    void* __restrict__ C, int ldc, int nby) {
  __shared__ unsigned short smem[16640];  // 33.28KB
  char* const smc = (char*)smem;

  const int tid = threadIdx.x;
  const int w = tid >> 6, lane = tid & 63;
  const int cpx = gridDim.x >> 3;
  const int g = blockIdx.x;
  const int sw = (g & 7) * cpx + (g >> 3);
  const int bx = sw / nby, by = sw - bx * nby;
  const int tok0 = bx << 7, n0 = by << 7;

  const int wm = w >> 1, wn = w & 1;
  const int lrow = lane & 15, kgrp = lane >> 4;

  const int lr4 = lane >> 2;
  const int r0 = (w * 2 + 0) * 16 + lr4;
  const int r1 = (w * 2 + 1) * 16 + lr4;
  const int c0 = ((lane & 3) ^ ((r0 >> 1) & 3)) << 3;
  const int c1 = ((lane & 3) ^ ((r1 >> 1) & 3)) << 3;
  const unsigned short* A0 = A + (size_t)(tok0 + r0) * lda + c0;
  const unsigned short* A1p = A + (size_t)(tok0 + r1) * lda + c1;
  const unsigned short* B0 = Bt + (size_t)(n0 + r0) * ldb + c0;
  const unsigned short* B1 = Bt + (size_t)(n0 + r1) * ldb + c1;
  const int d0 = (w * 2 + 0) * 1024;
  const int d1 = (w * 2 + 1) * 1024;

  f32x4 acc[4][4];
#pragma unroll
  for (int i = 0; i < 4; i++)
#pragma unroll
    for (int j = 0; j < 4; j++) {
      f32x4 z = {0.f, 0.f, 0.f, 0.f};
      acc[i][j] = z;
    }

  const int nt = KT >> 5;
  gload16(A0, smc + d0);
  gload16(A1p, smc + d1);
  gload16(B0, smc + 16384 + d0);
  gload16(B1, smc + 16384 + d1);
  __syncthreads();

  int buf = 0;
  for (int t = 0; t < nt; t++) {
    if (t + 1 < nt) {
      const int kt = (t + 1) << 5;
      const int bo = (buf ^ 1) * 8192;
      gload16(A0 + kt, smc + bo + d0);
      gload16(A1p + kt, smc + bo + d1);
      gload16(B0 + kt, smc + 16384 + bo + d0);
      gload16(B1 + kt, smc + 16384 + bo + d1);
    }
    const int bo = buf * 8192;
    bf16x8 af[4], bf_[4];
#pragma unroll
    for (int f = 0; f < 4; f++) {
      const int ra = wm * 64 + f * 16 + lrow;
      const int rb = wn * 64 + f * 16 + lrow;
      af[f] = *(const bf16x8*)(smc + bo + ra * 64 +
                               ((kgrp ^ ((ra >> 1) & 3)) << 4));
      bf_[f] = *(const bf16x8*)(smc + 16384 + bo + rb * 64 +
                                ((kgrp ^ ((rb >> 1) & 3)) << 4));
    }
#pragma unroll
    for (int mf = 0; mf < 4; mf++)
#pragma unroll
      for (int nf = 0; nf < 4; nf++)
        acc[mf][nf] = __builtin_amdgcn_mfma_f32_16x16x32_bf16(
            af[mf], bf_[nf], acc[mf][nf], 0, 0, 0);
    __syncthreads();
    buf ^= 1;
  }

  if constexpr (EPI == 3) {
#pragma unroll
    for (int mf = 0; mf < 4; mf++)
#pragma unroll
      for (int nf = 0; nf < 4; nf++) {
        const int cl = wn * 64 + nf * 16 + lrow;
        const float bv = bias[n0 + cl];
#pragma unroll
        for (int r = 0; r < 4; r++) {
          const int tl = wm * 64 + mf * 16 + kgrp * 4 + r;
          smem[(cl >> 2) * 520 + tl * 4 + (cl & 3)] =
              f2bf(acc[mf][nf][r] + bv);
        }
      }
    __syncthreads();
    const int bb_ = tok0 >> 12, pos0 = tok0 & 4095, cg0 = n0 >> 2;
    uint2* Cb = (uint2*)C;
#pragma unroll
    for (int e = 0; e < 16; e++) {
      const int lin = e * 256 + tid;
      const int cgl = lin >> 7, pp = lin & 127;
      const uint2 v = *(const uint2*)&smem[cgl * 520 + pp * 4];
      Cb[((size_t)(cg0 + cgl) * 16 + bb_) * 4096 + pos0 + pp] = v;
    }
  } else {
#pragma unroll
    for (int mf = 0; mf < 4; mf++) {
#pragma unroll
      for (int nf = 0; nf < 4; nf++) {
        const int gcol = n0 + wn * 64 + nf * 16 + lrow;
        const float bv = bias ? bias[gcol] : 0.0f;
#pragma unroll
        for (int r = 0; r < 4; r++) {
          const int grow = tok0 + wm * 64 + mf * 16 + kgrp * 4 + r;
          float v = acc[mf][nf][r] + bv;
          const size_t idx = (size_t)grow * ldc + gcol;
          if constexpr (EPI == 1) {
            ((float*)C)[idx] = v + res[idx];
          } else {
            const float z = 1.5957691216057308f * (v + 0.044715f * v * v * v);
            const float gl = v / (1.0f + __expf(-z));
            ((unsigned short*)C)[idx] = f2bf(gl);
          }
        }
      }
    }
  }
}

// ---------- segmented bidirectional EMA, float results ----------
__device__ __forceinline__ void ema_seg_f(const unsigned int vals[16],
                                          const int seg, float rl[16],
                                          float rh[16]) {
  const float A16 = 2.8211099e-4f;   // 0.6^16
  const float A32 = 7.9586611e-8f;   // 0.6^32
  float a, bv, t;
  float za = 0.f, zb = 0.f;
#pragma unroll
  for (int j = 0; j < 16; j++) {
    unpack2(vals[j], a, bv);
    za = 0.6f * za + 0.4f * a;
    zb = 0.6f * zb + 0.4f * bv;
  }
  t = __shfl_up(za, 1); if (seg >= 1) za += A16 * t;
  t = __shfl_up(zb, 1); if (seg >= 1) zb += A16 * t;
  t = __shfl_up(za, 2); if (seg >= 2) za += A32 * t;
  t = __shfl_up(zb, 2); if (seg >= 2) zb += A32 * t;
  float yfa = __shfl_up(za, 1), yfb = __shfl_up(zb, 1);
  if (seg == 0) { yfa = 0.f; yfb = 0.f; }
  float ua = 0.f, ub = 0.f;
#pragma unroll
  for (int j = 15; j >= 0; j--) {
    unpack2(vals[j], a, bv);
    ua = 0.6f * ua + 0.4f * a;
    ub = 0.6f * ub + 0.4f * bv;
  }
  t = __shfl_down(ua, 1); if (seg <= 2) ua += A16 * t;
  t = __shfl_down(ub, 1); if (seg <= 2) ub += A16 * t;
  t = __shfl_down(ua, 2); if (seg <= 1) ua += A32 * t;
  t = __shfl_down(ub, 2); if (seg <= 1) ub += A32 * t;
  float zba = __shfl_down(ua, 1), zbb = __shfl_down(ub, 1);
  if (seg == 3) { zba = 0.f; zbb = 0.f; }
  float fa = yfa, fb = yfb;
#pragma unroll
  for (int j = 0; j < 16; j++) {
    unpack2(vals[j], a, bv);
    fa = 0.6f * fa + 0.4f * a;
    fb = 0.6f * fb + 0.4f * bv;
    rl[j] = fa;
    rh[j] = fb;
  }
  float ga = zba, gb = zbb;
#pragma unroll
  for (int j = 15; j >= 0; j--) {
    unpack2(vals[j], a, bv);
    ga = 0.6f * ga + 0.4f * a;
    gb = 0.6f * gb + 0.4f * bv;
    rl[j] = 0.25f * (rl[j] + ga);
    rh[j] = 0.25f * (rh[j] + gb);
  }
}

// ---------- fused dwconv3x3 + 4 EMA scans on bundle8 layout ----------
// 512 threads. Input staged to LDS (inp) in one coalesced pass; conv taps
// read LDS instead of L1/L2. LDS 66.6KB -> 2 blocks/CU (same as before,
// VGPR-capped anyway).
__global__ __launch_bounds__(512) void conv_scan_kernel(
    const uint2* __restrict__ p, const float* __restrict__ kconv,
    uint2* __restrict__ mixed) {
  __shared__ unsigned int inp[2][64][65];  // 33.28 KB input stage
  __shared__ unsigned int loc[2][64][65];  // 33.28 KB conv/scan buffer
  __shared__ float klds[36];
  const int tid = threadIdx.x;
  const int c = blockIdx.x;   // cell 0..191
  const int b = blockIdx.y;   // 0..15
  const uint2* pb = p + ((size_t)c * 16 + b) * 4096;

  if (tid < 36) klds[tid] = kconv[(tid >> 2) * DINNER + c * 4 + (tid & 3)];

  // stage input plane (coalesced, one pass)
#pragma unroll
  for (int i = 0; i < 8; i++) {
    const int pos = tid + 512 * i;
    const int h = pos >> 6, w = pos & 63;
    const uint2 pv = pb[pos];
    inp[0][h][w] = pv.x;
    inp[1][h][w] = pv.y;
  }
  __syncthreads();

  // conv from LDS
#pragma unroll 2
  for (int i = 0; i < 8; i++) {
    const int pos = tid + 512 * i;
    const int h = pos >> 6, w = pos & 63;
    float a0 = 0.f, a1 = 0.f, a2 = 0.f, a3 = 0.f;
#pragma unroll
    for (int dh = 0; dh < 3; dh++) {
      const int hh = h + dh - 1;
      const bool vh = (unsigned)hh < 64u;
      const int hcl = min(max(hh, 0), 63);
#pragma unroll
      for (int dw = 0; dw < 3; dw++) {
        const int ww = w + dw - 1;
        const bool vv = vh && ((unsigned)ww < 64u);
        const int wcl = min(max(ww, 0), 63);
        unsigned int ux = inp[0][hcl][wcl];
        unsigned int uy = inp[1][hcl][wcl];
        if (!vv) { ux = 0; uy = 0; }
        const int t = dh * 3 + dw;
        float lo, hi;
        unpack2(ux, lo, hi);
        a0 += lo * klds[t * 4 + 0];
        a1 += hi * klds[t * 4 + 1];
        unpack2(uy, lo, hi);
        a2 += lo * klds[t * 4 + 2];
        a3 += hi * klds[t * 4 + 3];
      }
    }
    loc[0][h][w] = pack2t(a0, a1);
    loc[1][h][w] = pack2t(a2, a3);
  }
  __syncthreads();

  const int seg = tid & 3;
  const int ax = (tid >> 2) & 63;
  const int cp = tid >> 8;
  const int j0 = seg * 16;

  float hcl_[16], hch_[16];
  {
    unsigned int vals[16];
#pragma unroll
    for (int j = 0; j < 16; j++) vals[j] = loc[cp][j0 + j][ax];
    ema_seg_f(vals, seg, hcl_, hch_);
  }
  __syncthreads();

  {
    unsigned int vals[16];
    float wl[16], wh[16];
#pragma unroll
    for (int j = 0; j < 16; j++) vals[j] = loc[cp][ax][j0 + j];
    ema_seg_f(vals, seg, wl, wh);
#pragma unroll
    for (int j = 0; j < 16; j++) {
      float a, bv;
      unpack2(vals[j], a, bv);
      loc[cp][ax][j0 + j] = pack2t(a + wl[j], bv + wh[j]);
    }
  }
  __syncthreads();

#pragma unroll
  for (int j = 0; j < 16; j++) {
    float a, bv;
    unpack2(loc[cp][j0 + j][ax], a, bv);
    loc[cp][j0 + j][ax] = pack2t(a + hcl_[j], bv + hch_[j]);
  }
  __syncthreads();

  uint2* mb = mixed + ((size_t)c * 16 + b) * 4096;
#pragma unroll
  for (int i = 0; i < 8; i++) {
    const int pos = tid + 512 * i;
    const int h = pos >> 6, w = pos & 63;
    uint2 st;
    st.x = loc[0][h][w];
    st.y = loc[1][h][w];
    mb[pos] = st;
  }
}

extern "C" void kernel_launch(void* const* d_in, const int* in_sizes, int n_in,
                              void* d_out, int out_size, void* d_ws,
                              size_t ws_size, hipStream_t stream) {
  const float* x = (const float*)d_in[0];
  const float* n1_g = (const float*)d_in[1];
  const float* n1_b = (const float*)d_in[2];
  const float* w_in = (const float*)d_in[3];
  const float* b_in = (const float*)d_in[4];
  const float* k_conv = (const float*)d_in[5];
  const float* on_g = (const float*)d_in[6];
  const float* on_b = (const float*)d_in[7];
  const float* w_out = (const float*)d_in[8];
  const float* b_out = (const float*)d_in[9];
  const float* n2_g = (const float*)d_in[10];
  const float* n2_b = (const float*)d_in[11];
  const float* w1 = (const float*)d_in[12];
  const float* b1 = (const float*)d_in[13];
  const float* w2 = (const float*)d_in[14];
  const float* b2 = (const float*)d_in[15];

  const size_t MB = 1024 * 1024;
  char* ws = (char*)d_ws;
  unsigned short* R1 = (unsigned short*)(ws + 3 * MB / 2);
  unsigned short* R2 = (unsigned short*)(ws + 3 * MB / 2 + 96 * MB);

  unsigned short* A1 = R2;                         // 48MB token-major
  unsigned short* wTin = R2 + (48 * MB) / 2;       // [768][384]
  unsigned short* p = R1;                          // 96MB BUNDLE8; in-place
  unsigned short* A2 = R2;                         // 96MB token-major
  unsigned short* wTout = R1;                      // [384][768] (p dead)
  unsigned short* A3 = R1;                         // 48MB
  unsigned short* wT1 = R1 + (48 * MB) / 2;        // [1536][384]
  unsigned short* wT2 = wT1 + (size_t)1536 * 384;  // [384][1536]
  unsigned short* gb = R2;                         // 96MB token-major

  float* out = (float*)d_out;
  dim3 b256(256);

  // LN1(x) -> A1, merged with w_in^T prep (disjoint R2 regions)
  ln1_wprep_kernel<<<16384 + 288, b256, 0, stream>>>(x, n1_g, n1_b, A1, w_in,
                                                     wTin);
  // p(bundle8) = A1 @ w_in + b_in
  gemm_bt_kernel<3><<<3072, b256, 0, stream>>>(A1, DMODEL, wTin, DMODEL, DMODEL,
                                               b_in, nullptr, p, DINNER, 6);
  // mixed(bundle8) = conv+scan(p), in place
  conv_scan_kernel<<<dim3(192, 16), dim3(512), 0, stream>>>(
      (const uint2*)p, k_conv, (uint2*)p);
  // LN(on)(mixed bundle8) -> A2 token-major
  ln_bundle_768<<<1024, b256, 0, stream>>>((const uint2*)p, on_g, on_b,
                                           (uint2*)A2);
  // merged prep: w_out^T, w1^T, w2^T (p dead after ln_bundle)
  wprep3_kernel<<<1440, b256, 0, stream>>>(w_out, wTout, w1, wT1, w2, wT2);
  // out = x + A2 @ w_out + b_out
  gemm_bt_kernel<1><<<1536, b256, 0, stream>>>(A2, DINNER, wTout, DINNER, DINNER,
                                               b_out, x, out, DMODEL, 3);
  // LN2(out) -> A3
  ln_fused_f32_384<<<T_TOKENS / 4, b256, 0, stream>>>(out, n2_g, n2_b, A3);
  // MLP split by tokens
  for (int hh = 0; hh < 2; hh++) {
    const size_t toff = (size_t)hh * 32768;
    gemm_bt_kernel<2><<<3072, b256, 0, stream>>>(
        A3 + toff * DMODEL, DMODEL, wT1, DMODEL, DMODEL, b1, nullptr, gb,
        DHIDDEN, 12);
    gemm_bt_kernel<1><<<768, b256, 0, stream>>>(
        gb, DHIDDEN, wT2, DHIDDEN, DHIDDEN, b2, out + toff * DMODEL,
        out + toff * DMODEL, DMODEL, 3);
  }
}

// Round 20
// 621.806 us; speedup vs baseline: 1.0516x; 1.0314x over previous
//
#include <hip/hip_runtime.h>
#include <math.h>

// LegacyVMambaBlock R20: bf16 residual trunk. x2 stored as bf16 (x2b, 48MB,
// R1 start) instead of f32 in d_out: G2 EPI=4 (bf16 store + f32 residual),
// LN2 reads bf16, G4 EPI=5 (f32 store + bf16 residual). A3 lives in upper
// half of d_out (stream-ordered, no collision; d_out fully rewritten).
// Saves ~144MB HBM traffic. Everything else = R19 proven.

typedef __attribute__((ext_vector_type(8))) short bf16x8;
typedef __attribute__((ext_vector_type(4))) float f32x4;

#define T_TOKENS 65536
#define DMODEL 384
#define DINNER 768
#define DHIDDEN 1536

__device__ __forceinline__ float bf2f(unsigned short u) {
  unsigned int x = ((unsigned int)u) << 16;
  return __builtin_bit_cast(float, x);
}
__device__ __forceinline__ unsigned short f2bf(float f) {
  unsigned int x = __builtin_bit_cast(unsigned int, f);
  x += 0x7fffu + ((x >> 16) & 1u);
  return (unsigned short)(x >> 16);
}
__device__ __forceinline__ void unpack2(unsigned int u, float& lo, float& hi) {
  lo = __builtin_bit_cast(float, u << 16);
  hi = __builtin_bit_cast(float, u & 0xffff0000u);
}
__device__ __forceinline__ unsigned int pack2(float lo, float hi) {
  return (unsigned int)f2bf(lo) | ((unsigned int)f2bf(hi) << 16);
}
// truncating pack (3 ops): <=1 ULP bf16 noise, conv_scan-internal only
__device__ __forceinline__ unsigned int pack2t(float lo, float hi) {
  return (__builtin_bit_cast(unsigned int, lo) >> 16) |
         (__builtin_bit_cast(unsigned int, hi) & 0xffff0000u);
}

__device__ __forceinline__ void gload16(const void* g, void* l) {
  __builtin_amdgcn_global_load_lds(
      (const __attribute__((address_space(1))) void*)g,
      (__attribute__((address_space(3))) void*)l, 16, 0, 0);
}

// ---------- weight prep helper ----------
__device__ __forceinline__ void wprep_tile(const float* __restrict__ in,
                                           unsigned short* __restrict__ out,
                                           int K, int N, int k0, int n0,
                                           int tid, float t[32][33]) {
  const int a = tid & 31, b8 = tid >> 5;
#pragma unroll
  for (int i = 0; i < 4; i++)
    t[b8 + 8 * i][a] = in[(size_t)(k0 + b8 + 8 * i) * N + n0 + a];
  __syncthreads();
#pragma unroll
  for (int i = 0; i < 4; i++)
    out[(size_t)(n0 + b8 + 8 * i) * K + k0 + a] = f2bf(t[a][b8 + 8 * i]);
}

// ---------- fused LN over f32 [T,384] -> bf16 + w_in prep (merged) ----------
__global__ __launch_bounds__(256) void ln1_wprep_kernel(
    const float* __restrict__ in, const float* __restrict__ g,
    const float* __restrict__ b, unsigned short* __restrict__ out,
    const float* __restrict__ win, unsigned short* __restrict__ wTin) {
  __shared__ float t[32][33];
  if (blockIdx.x >= 16384) {
    const int id = blockIdx.x - 16384;  // 288 tiles: 12 x 24
    wprep_tile(win, wTin, DMODEL, DINNER, (id % 12) * 32, (id / 12) * 32,
               threadIdx.x, t);
    return;
  }
  const int tok = blockIdx.x * 4 + (threadIdx.x >> 6);
  const int lane = threadIdx.x & 63;
  const float2* row = (const float2*)(in + (size_t)tok * 384);
  float2 v[3];
  float s = 0.f, ss = 0.f;
#pragma unroll
  for (int k = 0; k < 3; k++) {
    v[k] = row[lane + 64 * k];
    s += v[k].x + v[k].y;
    ss += v[k].x * v[k].x + v[k].y * v[k].y;
  }
#pragma unroll
  for (int off = 32; off > 0; off >>= 1) {
    s += __shfl_xor(s, off);
    ss += __shfl_xor(ss, off);
  }
  const float m = s * (1.0f / 384.0f);
  const float r = rsqrtf(ss * (1.0f / 384.0f) - m * m + 1e-5f);
  unsigned int* op = (unsigned int*)(out + (size_t)tok * 384);
#pragma unroll
  for (int k = 0; k < 3; k++) {
    const int c = lane + 64 * k;
    const float2 gg = ((const float2*)g)[c];
    const float2 bb = ((const float2*)b)[c];
    op[c] = pack2((v[k].x - m) * r * gg.x + bb.x, (v[k].y - m) * r * gg.y + bb.y);
  }
}

// ---------- fused LN over bf16 [T,384] -> bf16 (LN2 on x2b) ----------
__global__ __launch_bounds__(256) void ln_fused_bf16_384(
    const unsigned short* __restrict__ in, const float* __restrict__ g,
    const float* __restrict__ b, unsigned short* __restrict__ out) {
  const int tok = blockIdx.x * 4 + (threadIdx.x >> 6);
  const int lane = threadIdx.x & 63;
  const unsigned int* row = (const unsigned int*)(in + (size_t)tok * 384);
  unsigned int u[3];
  float e[3][2];
  float s = 0.f, ss = 0.f;
#pragma unroll
  for (int k = 0; k < 3; k++) {
    u[k] = row[lane + 64 * k];
    unpack2(u[k], e[k][0], e[k][1]);
    s += e[k][0] + e[k][1];
    ss += e[k][0] * e[k][0] + e[k][1] * e[k][1];
  }
#pragma unroll
  for (int off = 32; off > 0; off >>= 1) {
    s += __shfl_xor(s, off);
    ss += __shfl_xor(ss, off);
  }
  const float m = s * (1.0f / 384.0f);
  const float r = rsqrtf(ss * (1.0f / 384.0f) - m * m + 1e-5f);
  unsigned int* op = (unsigned int*)(out + (size_t)tok * 384);
#pragma unroll
  for (int k = 0; k < 3; k++) {
    const int c = lane + 64 * k;
    const float2 gg = ((const float2*)g)[c];
    const float2 bb = ((const float2*)b)[c];
    op[c] = pack2((e[k][0] - m) * r * gg.x + bb.x,
                  (e[k][1] - m) * r * gg.y + bb.y);
  }
}

// ---------- LN over bundle8 bf16 [cell192][b][pos][4ch] -> token-major ------
__global__ __launch_bounds__(256) void ln_bundle_768(
    const uint2* __restrict__ mixed, const float* __restrict__ g,
    const float* __restrict__ b, uint2* __restrict__ out) {
  const int tid = threadIdx.x;
  const int tk = tid >> 2, j = tid & 3;
  const int token = blockIdx.x * 64 + tk;
  const int bb_ = token >> 12, posb = token & 4095;
  const size_t slab = (size_t)bb_ * 4096 + posb;
  float s = 0.f, ss = 0.f;
#pragma unroll 1
  for (int cg = j; cg < 192; cg += 4) {
    const uint2 v = mixed[((size_t)cg * 16) * 4096 + slab];
    float e0, e1, e2, e3;
    unpack2(v.x, e0, e1);
    unpack2(v.y, e2, e3);
    s += (e0 + e1) + (e2 + e3);
    ss += e0 * e0 + e1 * e1 + e2 * e2 + e3 * e3;
  }
  s += __shfl_xor(s, 1); ss += __shfl_xor(ss, 1);
  s += __shfl_xor(s, 2); ss += __shfl_xor(ss, 2);
  const float m = s * (1.0f / 768.0f);
  const float r = rsqrtf(ss * (1.0f / 768.0f) - m * m + 1e-5f);
  const size_t tokbase = (size_t)token * 192;
#pragma unroll 1
  for (int cg = j; cg < 192; cg += 4) {
    const uint2 v = mixed[((size_t)cg * 16) * 4096 + slab];
    const float4 gg = ((const float4*)g)[cg];
    const float4 bb4 = ((const float4*)b)[cg];
    float e0, e1, e2, e3;
    unpack2(v.x, e0, e1);
    unpack2(v.y, e2, e3);
    uint2 o;
    o.x = pack2((e0 - m) * r * gg.x + bb4.x, (e1 - m) * r * gg.y + bb4.y);
    o.y = pack2((e2 - m) * r * gg.z + bb4.z, (e3 - m) * r * gg.w + bb4.w);
    out[tokbase + cg] = o;
  }
}

// merged prep of w_out^T, w1^T, w2^T (one launch; runs after ln_bundle)
__global__ __launch_bounds__(256) void wprep3_kernel(
    const float* __restrict__ wout, unsigned short* __restrict__ wToutp,
    const float* __restrict__ w1, unsigned short* __restrict__ wT1p,
    const float* __restrict__ w2, unsigned short* __restrict__ wT2p) {
  __shared__ float t[32][33];
  int id = blockIdx.x;
  if (id < 288) {  // w_out: K=768, N=384
    wprep_tile(wout, wToutp, 768, 384, (id / 12) * 32, (id % 12) * 32,
               threadIdx.x, t);
  } else if (id < 864) {  // w1: K=384, N=1536
    id -= 288;
    wprep_tile(w1, wT1p, 384, 1536, (id / 48) * 32, (id % 48) * 32,
               threadIdx.x, t);
  } else {  // w2: K=1536, N=384
    id -= 864;
    wprep_tile(w2, wT2p, 1536, 384, (id / 12) * 32, (id % 12) * 32,
               threadIdx.x, t);
  }
}

// ---------- GEMM BK=32 2-phase dbuf, 4 blocks/CU ----------
// EPI: 2=gelu bf16; 3=bundle8 bf16; 4=bf16 store + f32 residual;
//      5=f32 store + bf16 residual.
template <int EPI>
__global__ __launch_bounds__(256, 4) void gemm_bt_kernel(
    const unsigned short* __restrict__ A, int lda,
    const unsigned short* __restrict__ Bt, int ldb, int KT,
    const float* __restrict__ bias, const void* __restrict__ res,
    void* __restrict__ C, int ldc, int nby) {
  __shared__ unsigned short smem[16640];  // 33.28KB
  char* const smc = (char*)smem;

  const int tid = threadIdx.x;
  const int w = tid >> 6, lane = tid & 63;
  const int cpx = gridDim.x >> 3;
  const int g = blockIdx.x;
  const int sw = (g & 7) * cpx + (g >> 3);
  const int bx = sw / nby, by = sw - bx * nby;
  const int tok0 = bx << 7, n0 = by << 7;

  const int wm = w >> 1, wn = w & 1;
  const int lrow = lane & 15, kgrp = lane >> 4;

  const int lr4 = lane >> 2;
  const int r0 = (w * 2 + 0) * 16 + lr4;
  const int r1 = (w * 2 + 1) * 16 + lr4;
  const int c0 = ((lane & 3) ^ ((r0 >> 1) & 3)) << 3;
  const int c1 = ((lane & 3) ^ ((r1 >> 1) & 3)) << 3;
  const unsigned short* A0 = A + (size_t)(tok0 + r0) * lda + c0;
  const unsigned short* A1p = A + (size_t)(tok0 + r1) * lda + c1;
  const unsigned short* B0 = Bt + (size_t)(n0 + r0) * ldb + c0;
  const unsigned short* B1 = Bt + (size_t)(n0 + r1) * ldb + c1;
  const int d0 = (w * 2 + 0) * 1024;
  const int d1 = (w * 2 + 1) * 1024;

  f32x4 acc[4][4];
#pragma unroll
  for (int i = 0; i < 4; i++)
#pragma unroll
    for (int j = 0; j < 4; j++) {
      f32x4 z = {0.f, 0.f, 0.f, 0.f};
      acc[i][j] = z;
    }

  const int nt = KT >> 5;
  gload16(A0, smc + d0);
  gload16(A1p, smc + d1);
  gload16(B0, smc + 16384 + d0);
  gload16(B1, smc + 16384 + d1);
  __syncthreads();

  int buf = 0;
  for (int t = 0; t < nt; t++) {
    if (t + 1 < nt) {
      const int kt = (t + 1) << 5;
      const int bo = (buf ^ 1) * 8192;
      gload16(A0 + kt, smc + bo + d0);
      gload16(A1p + kt, smc + bo + d1);
      gload16(B0 + kt, smc + 16384 + bo + d0);
      gload16(B1 + kt, smc + 16384 + bo + d1);
    }
    const int bo = buf * 8192;
    bf16x8 af[4], bf_[4];
#pragma unroll
    for (int f = 0; f < 4; f++) {
      const int ra = wm * 64 + f * 16 + lrow;
      const int rb = wn * 64 + f * 16 + lrow;
      af[f] = *(const bf16x8*)(smc + bo + ra * 64 +
                               ((kgrp ^ ((ra >> 1) & 3)) << 4));
      bf_[f] = *(const bf16x8*)(smc + 16384 + bo + rb * 64 +
                                ((kgrp ^ ((rb >> 1) & 3)) << 4));
    }
#pragma unroll
    for (int mf = 0; mf < 4; mf++)
#pragma unroll
      for (int nf = 0; nf < 4; nf++)
        acc[mf][nf] = __builtin_amdgcn_mfma_f32_16x16x32_bf16(
            af[mf], bf_[nf], acc[mf][nf], 0, 0, 0);
    __syncthreads();
    buf ^= 1;
  }

  if constexpr (EPI == 3) {
#pragma unroll
    for (int mf = 0; mf < 4; mf++)
#pragma unroll
      for (int nf = 0; nf < 4; nf++) {
        const int cl = wn * 64 + nf * 16 + lrow;
        const float bv = bias[n0 + cl];
#pragma unroll
        for (int r = 0; r < 4; r++) {
          const int tl = wm * 64 + mf * 16 + kgrp * 4 + r;
          smem[(cl >> 2) * 520 + tl * 4 + (cl & 3)] =
              f2bf(acc[mf][nf][r] + bv);
        }
      }
    __syncthreads();
    const int bb_ = tok0 >> 12, pos0 = tok0 & 4095, cg0 = n0 >> 2;
    uint2* Cb = (uint2*)C;
#pragma unroll
    for (int e = 0; e < 16; e++) {
      const int lin = e * 256 + tid;
      const int cgl = lin >> 7, pp = lin & 127;
      const uint2 v = *(const uint2*)&smem[cgl * 520 + pp * 4];
      Cb[((size_t)(cg0 + cgl) * 16 + bb_) * 4096 + pos0 + pp] = v;
    }
  } else {
#pragma unroll
    for (int mf = 0; mf < 4; mf++) {
#pragma unroll
      for (int nf = 0; nf < 4; nf++) {
        const int gcol = n0 + wn * 64 + nf * 16 + lrow;
        const float bv = bias ? bias[gcol] : 0.0f;
#pragma unroll
        for (int r = 0; r < 4; r++) {
          const int grow = tok0 + wm * 64 + mf * 16 + kgrp * 4 + r;
          float v = acc[mf][nf][r] + bv;
          const size_t idx = (size_t)grow * ldc + gcol;
          if constexpr (EPI == 4) {
            // bf16 trunk store: x2b = bf16(x_f32 + v)
            ((unsigned short*)C)[idx] = f2bf(v + ((const float*)res)[idx]);
          } else if constexpr (EPI == 5) {
            // final store: out_f32 = bf16_res + v
            ((float*)C)[idx] = v + bf2f(((const unsigned short*)res)[idx]);
          } else {
            const float z = 1.5957691216057308f * (v + 0.044715f * v * v * v);
            const float gl = v / (1.0f + __expf(-z));
            ((unsigned short*)C)[idx] = f2bf(gl);
          }
        }
      }
    }
  }
}

// ---------- segmented bidirectional EMA, float results ----------
__device__ __forceinline__ void ema_seg_f(const unsigned int vals[16],
                                          const int seg, float rl[16],
                                          float rh[16]) {
  const float A16 = 2.8211099e-4f;   // 0.6^16
  const float A32 = 7.9586611e-8f;   // 0.6^32
  float a, bv, t;
  float za = 0.f, zb = 0.f;
#pragma unroll
  for (int j = 0; j < 16; j++) {
    unpack2(vals[j], a, bv);
    za = 0.6f * za + 0.4f * a;
    zb = 0.6f * zb + 0.4f * bv;
  }
  t = __shfl_up(za, 1); if (seg >= 1) za += A16 * t;
  t = __shfl_up(zb, 1); if (seg >= 1) zb += A16 * t;
  t = __shfl_up(za, 2); if (seg >= 2) za += A32 * t;
  t = __shfl_up(zb, 2); if (seg >= 2) zb += A32 * t;
  float yfa = __shfl_up(za, 1), yfb = __shfl_up(zb, 1);
  if (seg == 0) { yfa = 0.f; yfb = 0.f; }
  float ua = 0.f, ub = 0.f;
#pragma unroll
  for (int j = 15; j >= 0; j--) {
    unpack2(vals[j], a, bv);
    ua = 0.6f * ua + 0.4f * a;
    ub = 0.6f * ub + 0.4f * bv;
  }
  t = __shfl_down(ua, 1); if (seg <= 2) ua += A16 * t;
  t = __shfl_down(ub, 1); if (seg <= 2) ub += A16 * t;
  t = __shfl_down(ua, 2); if (seg <= 1) ua += A32 * t;
  t = __shfl_down(ub, 2); if (seg <= 1) ub += A32 * t;
  float zba = __shfl_down(ua, 1), zbb = __shfl_down(ub, 1);
  if (seg == 3) { zba = 0.f; zbb = 0.f; }
  float fa = yfa, fb = yfb;
#pragma unroll
  for (int j = 0; j < 16; j++) {
    unpack2(vals[j], a, bv);
    fa = 0.6f * fa + 0.4f * a;
    fb = 0.6f * fb + 0.4f * bv;
    rl[j] = fa;
    rh[j] = fb;
  }
  float ga = zba, gb = zbb;
#pragma unroll
  for (int j = 15; j >= 0; j--) {
    unpack2(vals[j], a, bv);
    ga = 0.6f * ga + 0.4f * a;
    gb = 0.6f * gb + 0.4f * bv;
    rl[j] = 0.25f * (rl[j] + ga);
    rh[j] = 0.25f * (rh[j] + gb);
  }
}

// ---------- fused dwconv3x3 + 4 EMA scans on bundle8 (R19 proven) ----------
__global__ __launch_bounds__(512) void conv_scan_kernel(
    const uint2* __restrict__ p, const float* __restrict__ kconv,
    uint2* __restrict__ mixed) {
  __shared__ unsigned int inp[2][64][65];  // 33.28 KB input stage
  __shared__ unsigned int loc[2][64][65];  // 33.28 KB conv/scan buffer
  __shared__ float klds[36];
  const int tid = threadIdx.x;
  const int c = blockIdx.x;   // cell 0..191
  const int b = blockIdx.y;   // 0..15
  const uint2* pb = p + ((size_t)c * 16 + b) * 4096;

  if (tid < 36) klds[tid] = kconv[(tid >> 2) * DINNER + c * 4 + (tid & 3)];

#pragma unroll
  for (int i = 0; i < 8; i++) {
    const int pos = tid + 512 * i;
    const int h = pos >> 6, w = pos & 63;
    const uint2 pv = pb[pos];
    inp[0][h][w] = pv.x;
    inp[1][h][w] = pv.y;
  }
  __syncthreads();

#pragma unroll 2
  for (int i = 0; i < 8; i++) {
    const int pos = tid + 512 * i;
    const int h = pos >> 6, w = pos & 63;
    float a0 = 0.f, a1 = 0.f, a2 = 0.f, a3 = 0.f;
#pragma unroll
    for (int dh = 0; dh < 3; dh++) {
      const int hh = h + dh - 1;
      const bool vh = (unsigned)hh < 64u;
      const int hcl = min(max(hh, 0), 63);
#pragma unroll
      for (int dw = 0; dw < 3; dw++) {
        const int ww = w + dw - 1;
        const bool vv = vh && ((unsigned)ww < 64u);
        const int wcl = min(max(ww, 0), 63);
        unsigned int ux = inp[0][hcl][wcl];
        unsigned int uy = inp[1][hcl][wcl];
        if (!vv) { ux = 0; uy = 0; }
        const int t = dh * 3 + dw;
        float lo, hi;
        unpack2(ux, lo, hi);
        a0 += lo * klds[t * 4 + 0];
        a1 += hi * klds[t * 4 + 1];
        unpack2(uy, lo, hi);
        a2 += lo * klds[t * 4 + 2];
        a3 += hi * klds[t * 4 + 3];
      }
    }
    loc[0][h][w] = pack2t(a0, a1);
    loc[1][h][w] = pack2t(a2, a3);
  }
  __syncthreads();

  const int seg = tid & 3;
  const int ax = (tid >> 2) & 63;
  const int cp = tid >> 8;
  const int j0 = seg * 16;

  float hcl_[16], hch_[16];
  {
    unsigned int vals[16];
#pragma unroll
    for (int j = 0; j < 16; j++) vals[j] = loc[cp][j0 + j][ax];
    ema_seg_f(vals, seg, hcl_, hch_);
  }
  __syncthreads();

  {
    unsigned int vals[16];
    float wl[16], wh[16];
#pragma unroll
    for (int j = 0; j < 16; j++) vals[j] = loc[cp][ax][j0 + j];
    ema_seg_f(vals, seg, wl, wh);
#pragma unroll
    for (int j = 0; j < 16; j++) {
      float a, bv;
      unpack2(vals[j], a, bv);
      loc[cp][ax][j0 + j] = pack2t(a + wl[j], bv + wh[j]);
    }
  }
  __syncthreads();

#pragma unroll
  for (int j = 0; j < 16; j++) {
    float a, bv;
    unpack2(loc[cp][j0 + j][ax], a, bv);
    loc[cp][j0 + j][ax] = pack2t(a + hcl_[j], bv + hch_[j]);
  }
  __syncthreads();

  uint2* mb = mixed + ((size_t)c * 16 + b) * 4096;
#pragma unroll
  for (int i = 0; i < 8; i++) {
    const int pos = tid + 512 * i;
    const int h = pos >> 6, w = pos & 63;
    uint2 st;
    st.x = loc[0][h][w];
    st.y = loc[1][h][w];
    mb[pos] = st;
  }
}

extern "C" void kernel_launch(void* const* d_in, const int* in_sizes, int n_in,
                              void* d_out, int out_size, void* d_ws,
                              size_t ws_size, hipStream_t stream) {
  const float* x = (const float*)d_in[0];
  const float* n1_g = (const float*)d_in[1];
  const float* n1_b = (const float*)d_in[2];
  const float* w_in = (const float*)d_in[3];
  const float* b_in = (const float*)d_in[4];
  const float* k_conv = (const float*)d_in[5];
  const float* on_g = (const float*)d_in[6];
  const float* on_b = (const float*)d_in[7];
  const float* w_out = (const float*)d_in[8];
  const float* b_out = (const float*)d_in[9];
  const float* n2_g = (const float*)d_in[10];
  const float* n2_b = (const float*)d_in[11];
  const float* w1 = (const float*)d_in[12];
  const float* b1 = (const float*)d_in[13];
  const float* w2 = (const float*)d_in[14];
  const float* b2 = (const float*)d_in[15];

  const size_t MB = 1024 * 1024;
  char* ws = (char*)d_ws;
  unsigned short* R1 = (unsigned short*)(ws + 3 * MB / 2);
  unsigned short* R2 = (unsigned short*)(ws + 3 * MB / 2 + 96 * MB);

  unsigned short* A1 = R2;                          // 48MB token-major
  unsigned short* wTin = R2 + (48 * MB) / 2;        // [768][384]
  unsigned short* p = R1;                           // 96MB BUNDLE8; in-place
  unsigned short* A2 = R2;                          // 96MB token-major
  unsigned short* x2b = R1;                         // 48MB bf16 trunk (p dead)
  unsigned short* wT1 = R1 + (48 * MB) / 2;         // [1536][384]
  unsigned short* wT2 = wT1 + (size_t)1536 * 384;   // [384][1536]
  unsigned short* wTout = wT2 + (size_t)384 * 1536; // [384][768]
  unsigned short* gb = R2;                          // 96MB token-major

  float* out = (float*)d_out;
  // A3 (bf16 LN2 output, 48MB) lives in the UPPER half of d_out (bytes
  // 48..96MB). Write order: LN2 -> G3h0 -> G4h0(writes 0..48) ->
  // G3h1(reads 72..96) -> G4h1(writes 48..96). Stream-ordered, no overlap.
  unsigned short* A3 = (unsigned short*)out + (48 * MB) / 2;
  dim3 b256(256);

  // LN1(x) -> A1, merged with w_in^T prep (disjoint R2 regions)
  ln1_wprep_kernel<<<16384 + 288, b256, 0, stream>>>(x, n1_g, n1_b, A1, w_in,
                                                     wTin);
  // p(bundle8) = A1 @ w_in + b_in
  gemm_bt_kernel<3><<<3072, b256, 0, stream>>>(A1, DMODEL, wTin, DMODEL, DMODEL,
                                               b_in, nullptr, p, DINNER, 6);
  // mixed(bundle8) = conv+scan(p), in place
  conv_scan_kernel<<<dim3(192, 16), dim3(512), 0, stream>>>(
      (const uint2*)p, k_conv, (uint2*)p);
  // LN(on)(mixed bundle8) -> A2 token-major
  ln_bundle_768<<<1024, b256, 0, stream>>>((const uint2*)p, on_g, on_b,
                                           (uint2*)A2);
  // merged prep: w_out^T, w1^T, w2^T (p dead after ln_bundle)
  wprep3_kernel<<<1440, b256, 0, stream>>>(w_out, wTout, w1, wT1, w2, wT2);
  // x2b(bf16) = x + A2 @ w_out + b_out   (EPI=4: bf16 store + f32 res)
  gemm_bt_kernel<4><<<1536, b256, 0, stream>>>(A2, DINNER, wTout, DINNER,
                                               DINNER, b_out, x, x2b, DMODEL,
                                               3);
  // LN2(x2b) -> A3 (upper half of d_out)
  ln_fused_bf16_384<<<T_TOKENS / 4, b256, 0, stream>>>(x2b, n2_g, n2_b, A3);
  // MLP split by tokens
  for (int hh = 0; hh < 2; hh++) {
    const size_t toff = (size_t)hh * 32768;
    gemm_bt_kernel<2><<<3072, b256, 0, stream>>>(
        A3 + toff * DMODEL, DMODEL, wT1, DMODEL, DMODEL, b1, nullptr, gb,
        DHIDDEN, 12);
    // out_f32 = x2b + g @ w2 + b2   (EPI=5: f32 store + bf16 res)
    gemm_bt_kernel<5><<<768, b256, 0, stream>>>(
        gb, DHIDDEN, wT2, DHIDDEN, DHIDDEN, b2, x2b + toff * DMODEL,
        out + toff * DMODEL, DMODEL, 3);
  }
}

// Round 21
// 609.132 us; speedup vs baseline: 1.0735x; 1.0208x over previous
//
#include <hip/hip_runtime.h>
#include <math.h>

// LegacyVMambaBlock R21: GEMM counted-vmcnt pipeline (T4-lite). 3 rotating
// BK=32 buffers (48KB LDS), prefetch depth 2; per K-step: s_waitcnt vmcnt(4)
// (own tile-t loads landed, t+1 in flight) + raw s_barrier + sched_barrier(0)
// — no vmcnt(0) drain in the main loop (the guide's measured ~20% stall).
// launch_bounds(256,3): 3 blk/CU x 48KB = 144KB LDS. All EPIs + all other
// kernels = R20 proven (bf16 trunk, bundle8, conv_scan LDS-staged).

typedef __attribute__((ext_vector_type(8))) short bf16x8;
typedef __attribute__((ext_vector_type(4))) float f32x4;

#define T_TOKENS 65536
#define DMODEL 384
#define DINNER 768
#define DHIDDEN 1536

__device__ __forceinline__ float bf2f(unsigned short u) {
  unsigned int x = ((unsigned int)u) << 16;
  return __builtin_bit_cast(float, x);
}
__device__ __forceinline__ unsigned short f2bf(float f) {
  unsigned int x = __builtin_bit_cast(unsigned int, f);
  x += 0x7fffu + ((x >> 16) & 1u);
  return (unsigned short)(x >> 16);
}
__device__ __forceinline__ void unpack2(unsigned int u, float& lo, float& hi) {
  lo = __builtin_bit_cast(float, u << 16);
  hi = __builtin_bit_cast(float, u & 0xffff0000u);
}
__device__ __forceinline__ unsigned int pack2(float lo, float hi) {
  return (unsigned int)f2bf(lo) | ((unsigned int)f2bf(hi) << 16);
}
// truncating pack (3 ops): <=1 ULP bf16 noise, conv_scan-internal only
__device__ __forceinline__ unsigned int pack2t(float lo, float hi) {
  return (__builtin_bit_cast(unsigned int, lo) >> 16) |
         (__builtin_bit_cast(unsigned int, hi) & 0xffff0000u);
}

__device__ __forceinline__ void gload16(const void* g, void* l) {
  __builtin_amdgcn_global_load_lds(
      (const __attribute__((address_space(1))) void*)g,
      (__attribute__((address_space(3))) void*)l, 16, 0, 0);
}

// ---------- weight prep helper ----------
__device__ __forceinline__ void wprep_tile(const float* __restrict__ in,
                                           unsigned short* __restrict__ out,
                                           int K, int N, int k0, int n0,
                                           int tid, float t[32][33]) {
  const int a = tid & 31, b8 = tid >> 5;
#pragma unroll
  for (int i = 0; i < 4; i++)
    t[b8 + 8 * i][a] = in[(size_t)(k0 + b8 + 8 * i) * N + n0 + a];
  __syncthreads();
#pragma unroll
  for (int i = 0; i < 4; i++)
    out[(size_t)(n0 + b8 + 8 * i) * K + k0 + a] = f2bf(t[a][b8 + 8 * i]);
}

// ---------- fused LN over f32 [T,384] -> bf16 + w_in prep (merged) ----------
__global__ __launch_bounds__(256) void ln1_wprep_kernel(
    const float* __restrict__ in, const float* __restrict__ g,
    const float* __restrict__ b, unsigned short* __restrict__ out,
    const float* __restrict__ win, unsigned short* __restrict__ wTin) {
  __shared__ float t[32][33];
  if (blockIdx.x >= 16384) {
    const int id = blockIdx.x - 16384;  // 288 tiles: 12 x 24
    wprep_tile(win, wTin, DMODEL, DINNER, (id % 12) * 32, (id / 12) * 32,
               threadIdx.x, t);
    return;
  }
  const int tok = blockIdx.x * 4 + (threadIdx.x >> 6);
  const int lane = threadIdx.x & 63;
  const float2* row = (const float2*)(in + (size_t)tok * 384);
  float2 v[3];
  float s = 0.f, ss = 0.f;
#pragma unroll
  for (int k = 0; k < 3; k++) {
    v[k] = row[lane + 64 * k];
    s += v[k].x + v[k].y;
    ss += v[k].x * v[k].x + v[k].y * v[k].y;
  }
#pragma unroll
  for (int off = 32; off > 0; off >>= 1) {
    s += __shfl_xor(s, off);
    ss += __shfl_xor(ss, off);
  }
  const float m = s * (1.0f / 384.0f);
  const float r = rsqrtf(ss * (1.0f / 384.0f) - m * m + 1e-5f);
  unsigned int* op = (unsigned int*)(out + (size_t)tok * 384);
#pragma unroll
  for (int k = 0; k < 3; k++) {
    const int c = lane + 64 * k;
    const float2 gg = ((const float2*)g)[c];
    const float2 bb = ((const float2*)b)[c];
    op[c] = pack2((v[k].x - m) * r * gg.x + bb.x, (v[k].y - m) * r * gg.y + bb.y);
  }
}

// ---------- fused LN over bf16 [T,384] -> bf16 (LN2 on x2b) ----------
__global__ __launch_bounds__(256) void ln_fused_bf16_384(
    const unsigned short* __restrict__ in, const float* __restrict__ g,
    const float* __restrict__ b, unsigned short* __restrict__ out) {
  const int tok = blockIdx.x * 4 + (threadIdx.x >> 6);
  const int lane = threadIdx.x & 63;
  const unsigned int* row = (const unsigned int*)(in + (size_t)tok * 384);
  unsigned int u[3];
  float e[3][2];
  float s = 0.f, ss = 0.f;
#pragma unroll
  for (int k = 0; k < 3; k++) {
    u[k] = row[lane + 64 * k];
    unpack2(u[k], e[k][0], e[k][1]);
    s += e[k][0] + e[k][1];
    ss += e[k][0] * e[k][0] + e[k][1] * e[k][1];
  }
#pragma unroll
  for (int off = 32; off > 0; off >>= 1) {
    s += __shfl_xor(s, off);
    ss += __shfl_xor(ss, off);
  }
  const float m = s * (1.0f / 384.0f);
  const float r = rsqrtf(ss * (1.0f / 384.0f) - m * m + 1e-5f);
  unsigned int* op = (unsigned int*)(out + (size_t)tok * 384);
#pragma unroll
  for (int k = 0; k < 3; k++) {
    const int c = lane + 64 * k;
    const float2 gg = ((const float2*)g)[c];
    const float2 bb = ((const float2*)b)[c];
    op[c] = pack2((e[k][0] - m) * r * gg.x + bb.x,
                  (e[k][1] - m) * r * gg.y + bb.y);
  }
}

// ---------- LN over bundle8 bf16 [cell192][b][pos][4ch] -> token-major ------
__global__ __launch_bounds__(256) void ln_bundle_768(
    const uint2* __restrict__ mixed, const float* __restrict__ g,
    const float* __restrict__ b, uint2* __restrict__ out) {
  const int tid = threadIdx.x;
  const int tk = tid >> 2, j = tid & 3;
  const int token = blockIdx.x * 64 + tk;
  const int bb_ = token >> 12, posb = token & 4095;
  const size_t slab = (size_t)bb_ * 4096 + posb;
  float s = 0.f, ss = 0.f;
#pragma unroll 1
  for (int cg = j; cg < 192; cg += 4) {
    const uint2 v = mixed[((size_t)cg * 16) * 4096 + slab];
    float e0, e1, e2, e3;
    unpack2(v.x, e0, e1);
    unpack2(v.y, e2, e3);
    s += (e0 + e1) + (e2 + e3);
    ss += e0 * e0 + e1 * e1 + e2 * e2 + e3 * e3;
  }
  s += __shfl_xor(s, 1); ss += __shfl_xor(ss, 1);
  s += __shfl_xor(s, 2); ss += __shfl_xor(ss, 2);
  const float m = s * (1.0f / 768.0f);
  const float r = rsqrtf(ss * (1.0f / 768.0f) - m * m + 1e-5f);
  const size_t tokbase = (size_t)token * 192;
#pragma unroll 1
  for (int cg = j; cg < 192; cg += 4) {
    const uint2 v = mixed[((size_t)cg * 16) * 4096 + slab];
    const float4 gg = ((const float4*)g)[cg];
    const float4 bb4 = ((const float4*)b)[cg];
    float e0, e1, e2, e3;
    unpack2(v.x, e0, e1);
    unpack2(v.y, e2, e3);
    uint2 o;
    o.x = pack2((e0 - m) * r * gg.x + bb4.x, (e1 - m) * r * gg.y + bb4.y);
    o.y = pack2((e2 - m) * r * gg.z + bb4.z, (e3 - m) * r * gg.w + bb4.w);
    out[tokbase + cg] = o;
  }
}

// merged prep of w_out^T, w1^T, w2^T (one launch; runs after ln_bundle)
__global__ __launch_bounds__(256) void wprep3_kernel(
    const float* __restrict__ wout, unsigned short* __restrict__ wToutp,
    const float* __restrict__ w1, unsigned short* __restrict__ wT1p,
    const float* __restrict__ w2, unsigned short* __restrict__ wT2p) {
  __shared__ float t[32][33];
  int id = blockIdx.x;
  if (id < 288) {  // w_out: K=768, N=384
    wprep_tile(wout, wToutp, 768, 384, (id / 12) * 32, (id % 12) * 32,
               threadIdx.x, t);
  } else if (id < 864) {  // w1: K=384, N=1536
    id -= 288;
    wprep_tile(w1, wT1p, 384, 1536, (id / 48) * 32, (id % 48) * 32,
               threadIdx.x, t);
  } else {  // w2: K=1536, N=384
    id -= 864;
    wprep_tile(w2, wT2p, 1536, 384, (id / 12) * 32, (id % 12) * 32,
               threadIdx.x, t);
  }
}

// ---------- GEMM BK=32, 3-buffer counted-vmcnt pipeline, 3 blocks/CU -------
// EPI: 2=gelu bf16; 3=bundle8 bf16; 4=bf16 store + f32 residual;
//      5=f32 store + bf16 residual.
template <int EPI>
__global__ __launch_bounds__(256, 3) void gemm_bt_kernel(
    const unsigned short* __restrict__ A, int lda,
    const unsigned short* __restrict__ Bt, int ldb, int KT,
    const float* __restrict__ bias, const void* __restrict__ res,
    void* __restrict__ C, int ldc, int nby) {
  __shared__ unsigned short smem[24576];  // 48KB: A 3x8KB | B 3x8KB @24KB
  char* const smc = (char*)smem;
  const int BOFF = 24576;  // byte offset of B buffers

  const int tid = threadIdx.x;
  const int w = tid >> 6, lane = tid & 63;
  const int cpx = gridDim.x >> 3;
  const int g = blockIdx.x;
  const int sw = (g & 7) * cpx + (g >> 3);
  const int bx = sw / nby, by = sw - bx * nby;
  const int tok0 = bx << 7, n0 = by << 7;

  const int wm = w >> 1, wn = w & 1;
  const int lrow = lane & 15, kgrp = lane >> 4;

  const int lr4 = lane >> 2;
  const int r0 = (w * 2 + 0) * 16 + lr4;
  const int r1 = (w * 2 + 1) * 16 + lr4;
  const int c0 = ((lane & 3) ^ ((r0 >> 1) & 3)) << 3;
  const int c1 = ((lane & 3) ^ ((r1 >> 1) & 3)) << 3;
  const unsigned short* A0 = A + (size_t)(tok0 + r0) * lda + c0;
  const unsigned short* A1p = A + (size_t)(tok0 + r1) * lda + c1;
  const unsigned short* B0 = Bt + (size_t)(n0 + r0) * ldb + c0;
  const unsigned short* B1 = Bt + (size_t)(n0 + r1) * ldb + c1;
  const int d0 = (w * 2 + 0) * 1024;
  const int d1 = (w * 2 + 1) * 1024;

  f32x4 acc[4][4];
#pragma unroll
  for (int i = 0; i < 4; i++)
#pragma unroll
    for (int j = 0; j < 4; j++) {
      f32x4 z = {0.f, 0.f, 0.f, 0.f};
      acc[i][j] = z;
    }

  const int nt = KT >> 5;
  // prologue: stage tiles 0 and 1 into buffers 0, 1 (8 gloads/wave in flight)
  {
    gload16(A0, smc + d0);
    gload16(A1p, smc + d1);
    gload16(B0, smc + BOFF + d0);
    gload16(B1, smc + BOFF + d1);
    const int kt = 32;
    gload16(A0 + kt, smc + 8192 + d0);
    gload16(A1p + kt, smc + 8192 + d1);
    gload16(B0 + kt, smc + BOFF + 8192 + d0);
    gload16(B1 + kt, smc + BOFF + 8192 + d1);
  }

  int buf = 0;
  for (int t = 0; t < nt; t++) {
    // wait for OWN tile-t loads (4); tile t+1's 4 may remain in flight
    if (t + 1 < nt) {
      asm volatile("s_waitcnt vmcnt(4)" ::: "memory");
    } else {
      asm volatile("s_waitcnt vmcnt(0)" ::: "memory");
    }
    __builtin_amdgcn_s_barrier();  // all waves: t landed; compute(t-1) done
    __builtin_amdgcn_sched_barrier(0);
    if (t + 2 < nt) {
      const int kt = (t + 2) << 5;
      const int so = ((t + 2) % 3) * 8192;
      gload16(A0 + kt, smc + so + d0);
      gload16(A1p + kt, smc + so + d1);
      gload16(B0 + kt, smc + BOFF + so + d0);
      gload16(B1 + kt, smc + BOFF + so + d1);
    }
    const int bo = buf * 8192;
    bf16x8 af[4], bf_[4];
#pragma unroll
    for (int f = 0; f < 4; f++) {
      const int ra = wm * 64 + f * 16 + lrow;
      const int rb = wn * 64 + f * 16 + lrow;
      af[f] = *(const bf16x8*)(smc + bo + ra * 64 +
                               ((kgrp ^ ((ra >> 1) & 3)) << 4));
      bf_[f] = *(const bf16x8*)(smc + BOFF + bo + rb * 64 +
                                ((kgrp ^ ((rb >> 1) & 3)) << 4));
    }
#pragma unroll
    for (int mf = 0; mf < 4; mf++)
#pragma unroll
      for (int nf = 0; nf < 4; nf++)
        acc[mf][nf] = __builtin_amdgcn_mfma_f32_16x16x32_bf16(
            af[mf], bf_[nf], acc[mf][nf], 0, 0, 0);
    buf = (buf + 1) % 3;
  }

  if constexpr (EPI == 3) {
    __syncthreads();  // all waves done with LDS before epilogue reuse
#pragma unroll
    for (int mf = 0; mf < 4; mf++)
#pragma unroll
      for (int nf = 0; nf < 4; nf++) {
        const int cl = wn * 64 + nf * 16 + lrow;
        const float bv = bias[n0 + cl];
#pragma unroll
        for (int r = 0; r < 4; r++) {
          const int tl = wm * 64 + mf * 16 + kgrp * 4 + r;
          smem[(cl >> 2) * 520 + tl * 4 + (cl & 3)] =
              f2bf(acc[mf][nf][r] + bv);
        }
      }
    __syncthreads();
    const int bb_ = tok0 >> 12, pos0 = tok0 & 4095, cg0 = n0 >> 2;
    uint2* Cb = (uint2*)C;
#pragma unroll
    for (int e = 0; e < 16; e++) {
      const int lin = e * 256 + tid;
      const int cgl = lin >> 7, pp = lin & 127;
      const uint2 v = *(const uint2*)&smem[cgl * 520 + pp * 4];
      Cb[((size_t)(cg0 + cgl) * 16 + bb_) * 4096 + pos0 + pp] = v;
    }
  } else {
#pragma unroll
    for (int mf = 0; mf < 4; mf++) {
#pragma unroll
      for (int nf = 0; nf < 4; nf++) {
        const int gcol = n0 + wn * 64 + nf * 16 + lrow;
        const float bv = bias ? bias[gcol] : 0.0f;
#pragma unroll
        for (int r = 0; r < 4; r++) {
          const int grow = tok0 + wm * 64 + mf * 16 + kgrp * 4 + r;
          float v = acc[mf][nf][r] + bv;
          const size_t idx = (size_t)grow * ldc + gcol;
          if constexpr (EPI == 4) {
            ((unsigned short*)C)[idx] = f2bf(v + ((const float*)res)[idx]);
          } else if constexpr (EPI == 5) {
            ((float*)C)[idx] = v + bf2f(((const unsigned short*)res)[idx]);
          } else {
            const float z = 1.5957691216057308f * (v + 0.044715f * v * v * v);
            const float gl = v / (1.0f + __expf(-z));
            ((unsigned short*)C)[idx] = f2bf(gl);
          }
        }
      }
    }
  }
}

// ---------- segmented bidirectional EMA, float results ----------
__device__ __forceinline__ void ema_seg_f(const unsigned int vals[16],
                                          const int seg, float rl[16],
                                          float rh[16]) {
  const float A16 = 2.8211099e-4f;   // 0.6^16
  const float A32 = 7.9586611e-8f;   // 0.6^32
  float a, bv, t;
  float za = 0.f, zb = 0.f;
#pragma unroll
  for (int j = 0; j < 16; j++) {
    unpack2(vals[j], a, bv);
    za = 0.6f * za + 0.4f * a;
    zb = 0.6f * zb + 0.4f * bv;
  }
  t = __shfl_up(za, 1); if (seg >= 1) za += A16 * t;
  t = __shfl_up(zb, 1); if (seg >= 1) zb += A16 * t;
  t = __shfl_up(za, 2); if (seg >= 2) za += A32 * t;
  t = __shfl_up(zb, 2); if (seg >= 2) zb += A32 * t;
  float yfa = __shfl_up(za, 1), yfb = __shfl_up(zb, 1);
  if (seg == 0) { yfa = 0.f; yfb = 0.f; }
  float ua = 0.f, ub = 0.f;
#pragma unroll
  for (int j = 15; j >= 0; j--) {
    unpack2(vals[j], a, bv);
    ua = 0.6f * ua + 0.4f * a;
    ub = 0.6f * ub + 0.4f * bv;
  }
  t = __shfl_down(ua, 1); if (seg <= 2) ua += A16 * t;
  t = __shfl_down(ub, 1); if (seg <= 2) ub += A16 * t;
  t = __shfl_down(ua, 2); if (seg <= 1) ua += A32 * t;
  t = __shfl_down(ub, 2); if (seg <= 1) ub += A32 * t;
  float zba = __shfl_down(ua, 1), zbb = __shfl_down(ub, 1);
  if (seg == 3) { zba = 0.f; zbb = 0.f; }
  float fa = yfa, fb = yfb;
#pragma unroll
  for (int j = 0; j < 16; j++) {
    unpack2(vals[j], a, bv);
    fa = 0.6f * fa + 0.4f * a;
    fb = 0.6f * fb + 0.4f * bv;
    rl[j] = fa;
    rh[j] = fb;
  }
  float ga = zba, gb = zbb;
#pragma unroll
  for (int j = 15; j >= 0; j--) {
    unpack2(vals[j], a, bv);
    ga = 0.6f * ga + 0.4f * a;
    gb = 0.6f * gb + 0.4f * bv;
    rl[j] = 0.25f * (rl[j] + ga);
    rh[j] = 0.25f * (rh[j] + gb);
  }
}

// ---------- fused dwconv3x3 + 4 EMA scans on bundle8 (R19 proven) ----------
__global__ __launch_bounds__(512) void conv_scan_kernel(
    const uint2* __restrict__ p, const float* __restrict__ kconv,
    uint2* __restrict__ mixed) {
  __shared__ unsigned int inp[2][64][65];  // 33.28 KB input stage
  __shared__ unsigned int loc[2][64][65];  // 33.28 KB conv/scan buffer
  __shared__ float klds[36];
  const int tid = threadIdx.x;
  const int c = blockIdx.x;   // cell 0..191
  const int b = blockIdx.y;   // 0..15
  const uint2* pb = p + ((size_t)c * 16 + b) * 4096;

  if (tid < 36) klds[tid] = kconv[(tid >> 2) * DINNER + c * 4 + (tid & 3)];

#pragma unroll
  for (int i = 0; i < 8; i++) {
    const int pos = tid + 512 * i;
    const int h = pos >> 6, w = pos & 63;
    const uint2 pv = pb[pos];
    inp[0][h][w] = pv.x;
    inp[1][h][w] = pv.y;
  }
  __syncthreads();

#pragma unroll 2
  for (int i = 0; i < 8; i++) {
    const int pos = tid + 512 * i;
    const int h = pos >> 6, w = pos & 63;
    float a0 = 0.f, a1 = 0.f, a2 = 0.f, a3 = 0.f;
#pragma unroll
    for (int dh = 0; dh < 3; dh++) {
      const int hh = h + dh - 1;
      const bool vh = (unsigned)hh < 64u;
      const int hcl = min(max(hh, 0), 63);
#pragma unroll
      for (int dw = 0; dw < 3; dw++) {
        const int ww = w + dw - 1;
        const bool vv = vh && ((unsigned)ww < 64u);
        const int wcl = min(max(ww, 0), 63);
        unsigned int ux = inp[0][hcl][wcl];
        unsigned int uy = inp[1][hcl][wcl];
        if (!vv) { ux = 0; uy = 0; }
        const int t = dh * 3 + dw;
        float lo, hi;
        unpack2(ux, lo, hi);
        a0 += lo * klds[t * 4 + 0];
        a1 += hi * klds[t * 4 + 1];
        unpack2(uy, lo, hi);
        a2 += lo * klds[t * 4 + 2];
        a3 += hi * klds[t * 4 + 3];
      }
    }
    loc[0][h][w] = pack2t(a0, a1);
    loc[1][h][w] = pack2t(a2, a3);
  }
  __syncthreads();

  const int seg = tid & 3;
  const int ax = (tid >> 2) & 63;
  const int cp = tid >> 8;
  const int j0 = seg * 16;

  float hcl_[16], hch_[16];
  {
    unsigned int vals[16];
#pragma unroll
    for (int j = 0; j < 16; j++) vals[j] = loc[cp][j0 + j][ax];
    ema_seg_f(vals, seg, hcl_, hch_);
  }
  __syncthreads();

  {
    unsigned int vals[16];
    float wl[16], wh[16];
#pragma unroll
    for (int j = 0; j < 16; j++) vals[j] = loc[cp][ax][j0 + j];
    ema_seg_f(vals, seg, wl, wh);
#pragma unroll
    for (int j = 0; j < 16; j++) {
      float a, bv;
      unpack2(vals[j], a, bv);
      loc[cp][ax][j0 + j] = pack2t(a + wl[j], bv + wh[j]);
    }
  }
  __syncthreads();

#pragma unroll
  for (int j = 0; j < 16; j++) {
    float a, bv;
    unpack2(loc[cp][j0 + j][ax], a, bv);
    loc[cp][j0 + j][ax] = pack2t(a + hcl_[j], bv + hch_[j]);
  }
  __syncthreads();

  uint2* mb = mixed + ((size_t)c * 16 + b) * 4096;
#pragma unroll
  for (int i = 0; i < 8; i++) {
    const int pos = tid + 512 * i;
    const int h = pos >> 6, w = pos & 63;
    uint2 st;
    st.x = loc[0][h][w];
    st.y = loc[1][h][w];
    mb[pos] = st;
  }
}

extern "C" void kernel_launch(void* const* d_in, const int* in_sizes, int n_in,
                              void* d_out, int out_size, void* d_ws,
                              size_t ws_size, hipStream_t stream) {
  const float* x = (const float*)d_in[0];
  const float* n1_g = (const float*)d_in[1];
  const float* n1_b = (const float*)d_in[2];
  const float* w_in = (const float*)d_in[3];
  const float* b_in = (const float*)d_in[4];
  const float* k_conv = (const float*)d_in[5];
  const float* on_g = (const float*)d_in[6];
  const float* on_b = (const float*)d_in[7];
  const float* w_out = (const float*)d_in[8];
  const float* b_out = (const float*)d_in[9];
  const float* n2_g = (const float*)d_in[10];
  const float* n2_b = (const float*)d_in[11];
  const float* w1 = (const float*)d_in[12];
  const float* b1 = (const float*)d_in[13];
  const float* w2 = (const float*)d_in[14];
  const float* b2 = (const float*)d_in[15];

  const size_t MB = 1024 * 1024;
  char* ws = (char*)d_ws;
  unsigned short* R1 = (unsigned short*)(ws + 3 * MB / 2);
  unsigned short* R2 = (unsigned short*)(ws + 3 * MB / 2 + 96 * MB);

  unsigned short* A1 = R2;                          // 48MB token-major
  unsigned short* wTin = R2 + (48 * MB) / 2;        // [768][384]
  unsigned short* p = R1;                           // 96MB BUNDLE8; in-place
  unsigned short* A2 = R2;                          // 96MB token-major
  unsigned short* x2b = R1;                         // 48MB bf16 trunk (p dead)
  unsigned short* wT1 = R1 + (48 * MB) / 2;         // [1536][384]
  unsigned short* wT2 = wT1 + (size_t)1536 * 384;   // [384][1536]
  unsigned short* wTout = wT2 + (size_t)384 * 1536; // [384][768]
  unsigned short* gb = R2;                          // 96MB token-major

  float* out = (float*)d_out;
  unsigned short* A3 = (unsigned short*)out + (48 * MB) / 2;
  dim3 b256(256);

  // LN1(x) -> A1, merged with w_in^T prep
  ln1_wprep_kernel<<<16384 + 288, b256, 0, stream>>>(x, n1_g, n1_b, A1, w_in,
                                                     wTin);
  // p(bundle8) = A1 @ w_in + b_in
  gemm_bt_kernel<3><<<3072, b256, 0, stream>>>(A1, DMODEL, wTin, DMODEL, DMODEL,
                                               b_in, nullptr, p, DINNER, 6);
  // mixed(bundle8) = conv+scan(p), in place
  conv_scan_kernel<<<dim3(192, 16), dim3(512), 0, stream>>>(
      (const uint2*)p, k_conv, (uint2*)p);
  // LN(on)(mixed bundle8) -> A2 token-major
  ln_bundle_768<<<1024, b256, 0, stream>>>((const uint2*)p, on_g, on_b,
                                           (uint2*)A2);
  // merged prep: w_out^T, w1^T, w2^T (p dead after ln_bundle)
  wprep3_kernel<<<1440, b256, 0, stream>>>(w_out, wTout, w1, wT1, w2, wT2);
  // x2b(bf16) = x + A2 @ w_out + b_out
  gemm_bt_kernel<4><<<1536, b256, 0, stream>>>(A2, DINNER, wTout, DINNER,
                                               DINNER, b_out, x, x2b, DMODEL,
                                               3);
  // LN2(x2b) -> A3 (upper half of d_out)
  ln_fused_bf16_384<<<T_TOKENS / 4, b256, 0, stream>>>(x2b, n2_g, n2_b, A3);
  // MLP split by tokens
  for (int hh = 0; hh < 2; hh++) {
    const size_t toff = (size_t)hh * 32768;
    gemm_bt_kernel<2><<<3072, b256, 0, stream>>>(
        A3 + toff * DMODEL, DMODEL, wT1, DMODEL, DMODEL, b1, nullptr, gb,
        DHIDDEN, 12);
    gemm_bt_kernel<5><<<768, b256, 0, stream>>>(
        gb, DHIDDEN, wT2, DHIDDEN, DHIDDEN, b2, x2b + toff * DMODEL,
        out + toff * DMODEL, DMODEL, 3);
  }
}